// Round 1
// baseline (2304.394 us; speedup 1.0000x reference)
//
#include <hip/hip_runtime.h>
#include <math.h>

#define DI __device__ __forceinline__

static constexpr int  B_ = 4, C_ = 256, N_ = 1024, L_ = 12, BL_ = 48;
static constexpr long SLAB = (long)N_ * C_;          // 262144 floats per (b,l)
static constexpr long TOT  = (long)BL_ * SLAB;       // 12,582,912 floats

// ---------------- block reductions (256 threads, 4 waves) ----------------
DI float block_sum256(float v, float* sc) {
    #pragma unroll
    for (int o = 32; o > 0; o >>= 1) v += __shfl_xor(v, o, 64);
    int wid = threadIdx.x >> 6;
    __syncthreads();
    if ((threadIdx.x & 63) == 0) sc[wid] = v;
    __syncthreads();
    return sc[0] + sc[1] + sc[2] + sc[3];
}
DI float block_max256(float v, float* sc) {
    #pragma unroll
    for (int o = 32; o > 0; o >>= 1) v = fmaxf(v, __shfl_xor(v, o, 64));
    int wid = threadIdx.x >> 6;
    __syncthreads();
    if ((threadIdx.x & 63) == 0) sc[wid] = v;
    __syncthreads();
    return fmaxf(fmaxf(sc[0], sc[1]), fmaxf(sc[2], sc[3]));
}

// ---------------- adp = softmax(relu(nv1@nv2), axis=1) ----------------
__global__ __launch_bounds__(256) void k_adp(const float* __restrict__ nv1,
                                             const float* __restrict__ nv2,
                                             float* __restrict__ adp) {
    __shared__ float r[6];
    __shared__ float sc[4];
    int row = blockIdx.x, tid = threadIdx.x;
    if (tid < 6) r[tid] = nv1[row * 6 + tid];
    __syncthreads();
    float e[4];
    #pragma unroll
    for (int q = 0; q < 4; q++) {
        int j = tid + q * 256;
        float s = 0.f;
        #pragma unroll
        for (int k = 0; k < 6; k++) s += r[k] * nv2[k * 1024 + j];
        e[q] = s > 0.f ? s : 0.f;
    }
    float m = fmaxf(fmaxf(e[0], e[1]), fmaxf(e[2], e[3]));
    m = block_max256(m, sc);
    float ps = 0.f;
    #pragma unroll
    for (int q = 0; q < 4; q++) { e[q] = __expf(e[q] - m); ps += e[q]; }
    ps = block_sum256(ps, sc);
    float rinv = 1.f / ps;
    #pragma unroll
    for (int q = 0; q < 4; q++) adp[(long)row * 1024 + tid + q * 256] = e[q] * rinv;
}

// ---------------- transpose in: x[b][c][n][l] -> xt[(b*12+l)][n][c] ----------------
__global__ __launch_bounds__(256) void k_tin(const float* __restrict__ x,
                                             float* __restrict__ xt) {
    __shared__ float t[64][65];
    int nl0 = blockIdx.x * 64, c0 = blockIdx.y * 64, b = blockIdx.z;
    int lx = threadIdx.x & 63, ly = threadIdx.x >> 6;
    #pragma unroll
    for (int i = 0; i < 16; i++) {
        int c = c0 + ly + i * 4;
        t[ly + i * 4][lx] = x[(long)(b * 256 + c) * 12288 + nl0 + lx];
    }
    __syncthreads();
    #pragma unroll
    for (int i = 0; i < 16; i++) {
        int nl = nl0 + ly + i * 4;
        int n = nl / 12, l = nl % 12;
        xt[((long)(b * 12 + l) * 1024 + n) * 256 + c0 + lx] = t[lx][ly + i * 4];
    }
}

// ---------------- weight/bias transpose: wt[n][c] = w[c][n]+1, bt[n][c] = b[c][n] ----
__global__ __launch_bounds__(256) void k_wtprep(const float* __restrict__ w,
                                                const float* __restrict__ b,
                                                float* __restrict__ wt,
                                                float* __restrict__ bt) {
    int n = blockIdx.x, c = threadIdx.x;
    wt[(long)n * 256 + c] = w[(long)c * 1024 + n] + 1.f;
    bt[(long)n * 256 + c] = b[(long)c * 1024 + n];
}

// ---------------- generic tiled fp32 GEMM ----------------
// C[bl][m][n] = sum over pairs: A_p[bl][m][k] * B_p(k,n)   (+bias[n])
// TRB=0: B[k*ldb + n]   TRB=1: B[n*ldb + koff + k]
// M=1024/batch, N=256, grid (16, 4, 48), 64x64 tile, 4x4 microtile, BK=16.
template<int TRB, int NPAIR, int KK>
__global__ __launch_bounds__(256) void k_gemm(
    const float* __restrict__ A0, long sA0,
    const float* __restrict__ B0, long sB0, int ldb0, int koff0,
    const float* __restrict__ A1, long sA1,
    const float* __restrict__ B1, long sB1, int ldb1, int koff1,
    const float* __restrict__ bias, float* __restrict__ Cout) {
    __shared__ float As[16][68];
    __shared__ float Bs[16][68];
    const int tid = threadIdx.x;
    const int bl = blockIdx.z;
    const int m0 = blockIdx.x * 64, n0 = blockIdx.y * 64;
    const int tm = (tid & 15) * 4, tn = (tid >> 4) * 4;
    const int ar = tid >> 2, ac = (tid & 3) * 4;   // A/BT staging: 64 rows x 4 k-quads
    const int br = tid >> 4, bc = (tid & 15) * 4;  // BN staging: 16 k x 16 n-quads
    float acc[4][4] = {};
    #pragma unroll
    for (int pair = 0; pair < NPAIR; pair++) {
        const float* A  = (pair ? A1 + (long)bl * sA1 : A0 + (long)bl * sA0);
        const float* Bm = (pair ? B1 + (long)bl * sB1 : B0 + (long)bl * sB0);
        const int ldb  = pair ? ldb1 : ldb0;
        const int koff = pair ? koff1 : koff0;
        for (int k0 = 0; k0 < KK; k0 += 16) {
            __syncthreads();
            float4 av = *(const float4*)&A[(long)(m0 + ar) * KK + k0 + ac];
            As[ac + 0][ar] = av.x; As[ac + 1][ar] = av.y;
            As[ac + 2][ar] = av.z; As[ac + 3][ar] = av.w;
            if (TRB) {
                float4 bv = *(const float4*)&Bm[(long)(n0 + ar) * ldb + koff + k0 + ac];
                Bs[ac + 0][ar] = bv.x; Bs[ac + 1][ar] = bv.y;
                Bs[ac + 2][ar] = bv.z; Bs[ac + 3][ar] = bv.w;
            } else {
                *(float4*)&Bs[br][bc] = *(const float4*)&Bm[(long)(k0 + br) * ldb + n0 + bc];
            }
            __syncthreads();
            #pragma unroll
            for (int k = 0; k < 16; k++) {
                float4 a = *(const float4*)&As[k][tm];
                float4 b = *(const float4*)&Bs[k][tn];
                float a4[4] = {a.x, a.y, a.z, a.w};
                float b4[4] = {b.x, b.y, b.z, b.w};
                #pragma unroll
                for (int i = 0; i < 4; i++)
                    #pragma unroll
                    for (int j = 0; j < 4; j++) acc[i][j] += a4[i] * b4[j];
            }
        }
    }
    float4 bb = bias ? *(const float4*)&bias[n0 + tn] : make_float4(0.f, 0.f, 0.f, 0.f);
    float* Cp = Cout + (long)bl * SLAB;
    #pragma unroll
    for (int i = 0; i < 4; i++) {
        float4 v = make_float4(acc[i][0] + bb.x, acc[i][1] + bb.y,
                               acc[i][2] + bb.z, acc[i][3] + bb.w);
        *(float4*)&Cp[(long)(m0 + tm + i) * 256 + n0 + tn] = v;
    }
}

// ---------------- Wh1/Wh2 row dots: o1[r]=Wh[r,:]·a[0:256], o2[r]=Wh[r,:]·a[256:512]
__global__ __launch_bounds__(256) void k_rowdot(const float* __restrict__ Wh,
                                                const float* __restrict__ a,
                                                float* __restrict__ o1,
                                                float* __restrict__ o2) {
    __shared__ float sc[4];
    long row = blockIdx.x;
    int tid = threadIdx.x;
    float v = Wh[row * 256 + tid];
    float s1 = block_sum256(v * a[tid], sc);
    float s2 = block_sum256(v * a[256 + tid], sc);
    if (tid == 0) { o1[row] = s1; o2[row] = s2; }
}

// ---------------- masked-softmax attention + P@Wh + elu ----------------
// grid (128, 48): block handles 8 query rows of one (b,l).
__global__ __launch_bounds__(256) void k_attn(const float* __restrict__ Wh,
                                              const float* __restrict__ w1v,
                                              const float* __restrict__ w2v,
                                              const int* __restrict__ dg,
                                              float* __restrict__ out) {
    __shared__ float e[8][1024];
    __shared__ float rs[8];
    int tid = threadIdx.x;
    int bl = blockIdx.y, i0 = blockIdx.x * 8;
    long base = (long)bl * 1024;
    float w1[8];
    #pragma unroll
    for (int i = 0; i < 8; i++) w1[i] = w1v[base + i0 + i];
    // phase A: scores, leaky-relu, mask
    #pragma unroll
    for (int q = 0; q < 4; q++) {
        int j = tid + q * 256;
        float w2 = w2v[base + j];
        #pragma unroll
        for (int i = 0; i < 8; i++) {
            int mk = dg[(long)(i0 + i) * 1024 + j];
            float ev = w1[i] + w2;
            ev = ev > 0.f ? ev : 0.2f * ev;
            e[i][j] = (mk > 0) ? ev : -9e15f;
        }
    }
    __syncthreads();
    // phase B: row softmax (wave per row, 2 rows/wave)
    int wid = tid >> 6, lane = tid & 63;
    #pragma unroll
    for (int rr = 0; rr < 2; rr++) {
        int i = wid + rr * 4;
        float m = -INFINITY;
        #pragma unroll
        for (int q = 0; q < 16; q++) m = fmaxf(m, e[i][lane + q * 64]);
        #pragma unroll
        for (int o = 32; o > 0; o >>= 1) m = fmaxf(m, __shfl_xor(m, o, 64));
        float s = 0.f;
        #pragma unroll
        for (int q = 0; q < 16; q++) {
            float p = __expf(e[i][lane + q * 64] - m);
            e[i][lane + q * 64] = p;
            s += p;
        }
        #pragma unroll
        for (int o = 32; o > 0; o >>= 1) s += __shfl_xor(s, o, 64);
        if (lane == 0) rs[i] = 1.f / s;
    }
    __syncthreads();
    // phase C: h'[i][c] = sum_j p[i][j] * Wh[j][c], c = tid
    float acc[8] = {};
    const float* wp = Wh + base * 256 + tid;
    #pragma unroll 4
    for (int j = 0; j < 1024; j++) {
        float w = wp[(long)j << 8];
        #pragma unroll
        for (int i = 0; i < 8; i++) acc[i] += e[i][j] * w;
    }
    #pragma unroll
    for (int i = 0; i < 8; i++) {
        float h = acc[i] * rs[i];
        h = h > 0.f ? h : __expf(h) - 1.f;   // elu
        out[(base + i0 + i) * 256 + tid] = h;
    }
}

// ---------------- fuse: a_s*gat + (1-a_s)*gcn + x ----------------
__global__ __launch_bounds__(256) void k_fuse(const float4* __restrict__ hp,
                                              const float4* __restrict__ gcn,
                                              const float4* __restrict__ xt,
                                              const float* __restrict__ alpha,
                                              float4* __restrict__ o) {
    long i = (long)blockIdx.x * 256 + threadIdx.x;
    float as = 1.f / (1.f + __expf(-alpha[0]));
    float bs = 1.f - as;
    float4 h = hp[i], g = gcn[i], x = xt[i];
    o[i] = make_float4(as * h.x + bs * g.x + x.x, as * h.y + bs * g.y + x.y,
                       as * h.z + bs * g.z + x.z, as * h.w + bs * g.w + x.w);
}

// ---------------- layernorm over each 262144-slab ----------------
__global__ __launch_bounds__(256) void k_ln_part(const float* __restrict__ x,
                                                 float2* __restrict__ part) {
    __shared__ float sc[4];
    int bl = blockIdx.y;
    const float4* p = (const float4*)(x + (long)bl * SLAB + (long)blockIdx.x * 4096);
    float s = 0.f, q = 0.f;
    #pragma unroll
    for (int i = 0; i < 4; i++) {
        float4 v = p[i * 256 + threadIdx.x];
        s += v.x + v.y + v.z + v.w;
        q += v.x * v.x + v.y * v.y + v.z * v.z + v.w * v.w;
    }
    s = block_sum256(s, sc);
    q = block_sum256(q, sc);
    if (threadIdx.x == 0) part[bl * 64 + blockIdx.x] = make_float2(s, q);
}

__global__ void k_ln_stats(const float2* __restrict__ part, float2* __restrict__ stats) {
    int bl = blockIdx.x;
    float2 v = part[bl * 64 + threadIdx.x];
    float s = v.x, q = v.y;
    #pragma unroll
    for (int o = 32; o > 0; o >>= 1) { s += __shfl_xor(s, o, 64); q += __shfl_xor(q, o, 64); }
    if (threadIdx.x == 0) {
        float mean = s / (float)SLAB;
        float var = q / (float)SLAB - mean * mean;
        stats[bl] = make_float2(mean, 1.f / sqrtf(var + 1e-5f));
    }
}

__global__ __launch_bounds__(256) void k_ln_apply(const float4* __restrict__ x,
                                                  const float2* __restrict__ stats,
                                                  float4* __restrict__ o) {
    long i = (long)blockIdx.x * 256 + threadIdx.x;
    int bl = (int)(i >> 16);           // SLAB/4 = 65536 float4 per slab
    float2 st = stats[bl];
    float4 v = x[i];
    o[i] = make_float4((v.x - st.x) * st.y, (v.y - st.x) * st.y,
                       (v.z - st.x) * st.y, (v.w - st.x) * st.y);
}

// ---------------- GLU elementwise: a *= sigmoid(c) ----------------
__global__ __launch_bounds__(256) void k_glumul(float4* __restrict__ a,
                                                const float4* __restrict__ c) {
    long i = (long)blockIdx.x * 256 + threadIdx.x;
    float4 av = a[i], cv = c[i];
    av.x *= 1.f / (1.f + __expf(-cv.x));
    av.y *= 1.f / (1.f + __expf(-cv.y));
    av.z *= 1.f / (1.f + __expf(-cv.z));
    av.w *= 1.f / (1.f + __expf(-cv.w));
    a[i] = av;
}

// ---------------- final pre-LN: (glu + xn)*(1+w) + bias ----------------
__global__ __launch_bounds__(256) void k_finpre(const float4* __restrict__ glu,
                                                const float4* __restrict__ xn,
                                                const float4* __restrict__ wt,
                                                const float4* __restrict__ bt,
                                                float4* __restrict__ o) {
    long i = (long)blockIdx.x * 256 + threadIdx.x;
    long wi = i & 65535;
    float4 g = glu[i], x = xn[i], w = wt[wi], b = bt[wi];
    o[i] = make_float4((g.x + x.x) * w.x + b.x, (g.y + x.y) * w.y + b.y,
                       (g.z + x.z) * w.z + b.z, (g.w + x.w) * w.w + b.w);
}

// ---------------- final normalize + transpose back to [b][c][n][l] ----------------
__global__ __launch_bounds__(256) void k_out(const float* __restrict__ x,
                                             const float2* __restrict__ stats,
                                             float* __restrict__ out) {
    int n = blockIdx.x, b = blockIdx.y, c = threadIdx.x;
    float v[12];
    #pragma unroll
    for (int l = 0; l < 12; l++) {
        float2 st = stats[b * 12 + l];
        float t = x[(long)(b * 12 + l) * SLAB + (long)n * 256 + c];
        v[l] = (t - st.x) * st.y;
    }
    float4* op = (float4*)(out + ((long)(b * 256 + c) * 1024 + n) * 12);
    op[0] = make_float4(v[0], v[1], v[2], v[3]);
    op[1] = make_float4(v[4], v[5], v[6], v[7]);
    op[2] = make_float4(v[8], v[9], v[10], v[11]);
}

// =================================================================
extern "C" void kernel_launch(void* const* d_in, const int* in_sizes, int n_in,
                              void* d_out, int out_size, void* d_ws, size_t ws_size,
                              hipStream_t stream) {
    (void)in_sizes; (void)n_in; (void)out_size; (void)ws_size;
    const float* x_in = (const float*)d_in[0];
    const int*   dg   = (const int*)d_in[1];
    const float* nv1  = (const float*)d_in[2];
    const float* nv2  = (const float*)d_in[3];
    const float* Wmlp = (const float*)d_in[4];
    const float* bmlp = (const float*)d_in[5];
    const float* Wg0  = (const float*)d_in[6];
    const float* ag0  = (const float*)d_in[7];
    const float* Wgo  = (const float*)d_in[8];
    const float* ago  = (const float*)d_in[9];
    const float* Wg1  = (const float*)d_in[10];
    const float* bg1  = (const float*)d_in[11];
    const float* Wg2  = (const float*)d_in[12];
    const float* bg2  = (const float*)d_in[13];
    const float* Wg3  = (const float*)d_in[14];
    const float* bg3  = (const float*)d_in[15];
    const float* alpha = (const float*)d_in[16];
    const float* wgt  = (const float*)d_in[17];
    const float* bia  = (const float*)d_in[18];
    float* out = (float*)d_out;

    float* ws = (float*)d_ws;
    float* XT  = ws;                    // [48][1024][256]
    float* A   = XT + TOT;
    float* Bb  = A + TOT;
    float* Cc  = Bb + TOT;
    float* ADP = Cc + TOT;              // [1024][1024]
    float* W1  = ADP + (long)1024 * 1024;   // [48*1024]
    float* W2  = W1 + 49152;
    float2* PART  = (float2*)(W2 + 49152);  // [48][64]
    float2* STATS = PART + 48 * 64;         // [48]
    float* WT  = (float*)(STATS + 48);      // [1024][256]
    float* BT2 = WT + SLAB;

    dim3 blk(256);
    k_wtprep<<<1024, blk, 0, stream>>>(wgt, bia, WT, BT2);
    k_adp<<<1024, blk, 0, stream>>>(nv1, nv2, ADP);
    k_tin<<<dim3(192, 4, 4), blk, 0, stream>>>(x_in, XT);
    // x1t = adp @ xt -> A
    k_gemm<0, 1, 1024><<<dim3(16, 4, 48), blk, 0, stream>>>(
        ADP, 0, XT, SLAB, 256, 0, nullptr, 0, nullptr, 0, 0, 0, nullptr, A);
    // gcn = [xt|x1t] @ W_mlp^T + b -> Bb
    k_gemm<1, 2, 256><<<dim3(16, 4, 48), blk, 0, stream>>>(
        XT, SLAB, Wmlp, 0, 512, 0, A, SLAB, Wmlp, 0, 512, 256, bmlp, Bb);
    // Wh (layer 1) = xt @ W_g0 -> A
    k_gemm<0, 1, 256><<<dim3(16, 4, 48), blk, 0, stream>>>(
        XT, SLAB, Wg0, 0, 256, 0, nullptr, 0, nullptr, 0, 0, 0, nullptr, A);
    k_rowdot<<<49152, blk, 0, stream>>>(A, ag0, W1, W2);
    k_attn<<<dim3(128, 48), blk, 0, stream>>>(A, W1, W2, dg, Cc);
    // Wh (layer 2) = g @ W_go -> A
    k_gemm<0, 1, 256><<<dim3(16, 4, 48), blk, 0, stream>>>(
        Cc, SLAB, Wgo, 0, 256, 0, nullptr, 0, nullptr, 0, 0, 0, nullptr, A);
    k_rowdot<<<49152, blk, 0, stream>>>(A, ago, W1, W2);
    k_attn<<<dim3(128, 48), blk, 0, stream>>>(A, W1, W2, dg, Cc);
    // fuse -> A
    k_fuse<<<12288, blk, 0, stream>>>((const float4*)Cc, (const float4*)Bb,
                                      (const float4*)XT, alpha, (float4*)A);
    // LN1: A -> Bb
    k_ln_part<<<dim3(64, 48), blk, 0, stream>>>(A, PART);
    k_ln_stats<<<48, 64, 0, stream>>>(PART, STATS);
    k_ln_apply<<<12288, blk, 0, stream>>>((const float4*)A, STATS, (float4*)Bb);
    // GLU
    k_gemm<1, 1, 256><<<dim3(16, 4, 48), blk, 0, stream>>>(
        Bb, SLAB, Wg1, 0, 256, 0, nullptr, 0, nullptr, 0, 0, 0, bg1, A);
    k_gemm<1, 1, 256><<<dim3(16, 4, 48), blk, 0, stream>>>(
        Bb, SLAB, Wg2, 0, 256, 0, nullptr, 0, nullptr, 0, 0, 0, bg2, Cc);
    k_glumul<<<12288, blk, 0, stream>>>((float4*)A, (const float4*)Cc);
    k_gemm<1, 1, 256><<<dim3(16, 4, 48), blk, 0, stream>>>(
        A, SLAB, Wg3, 0, 256, 0, nullptr, 0, nullptr, 0, 0, 0, bg3, Cc);
    // (glu + xn)*(1+w) + bias -> XT
    k_finpre<<<12288, blk, 0, stream>>>((const float4*)Cc, (const float4*)Bb,
                                        (const float4*)WT, (const float4*)BT2, (float4*)XT);
    // LN2 stats + normalize-transpose out
    k_ln_part<<<dim3(64, 48), blk, 0, stream>>>(XT, PART);
    k_ln_stats<<<48, 64, 0, stream>>>(PART, STATS);
    k_out<<<dim3(1024, 4), blk, 0, stream>>>(XT, STATS, out);
}

// Round 3
// 662.000 us; speedup vs baseline: 3.4810x; 3.4810x over previous
//
#include <hip/hip_runtime.h>
#include <math.h>

#define DI __device__ __forceinline__

static constexpr int  B_ = 4, C_ = 256, N_ = 1024, L_ = 12, BL_ = 48;
static constexpr long SLAB = (long)N_ * C_;          // 262144 elems per (b,l)
static constexpr long TOT  = (long)BL_ * SLAB;       // 12,582,912 elems

typedef __attribute__((ext_vector_type(8))) short bf16x8;
typedef __attribute__((ext_vector_type(4))) float f32x4;

DI float b2f(uint hw) { return __builtin_bit_cast(float, (hw & 0xffffu) << 16); }
DI ushort f2b(float f) {
    uint u = __builtin_bit_cast(uint, f);
    u += 0x7FFFu + ((u >> 16) & 1u);
    return (ushort)(u >> 16);
}

// ---------------- block reductions (256 threads, 4 waves) ----------------
DI float block_sum256(float v, float* sc) {
    #pragma unroll
    for (int o = 32; o > 0; o >>= 1) v += __shfl_xor(v, o, 64);
    int wid = threadIdx.x >> 6;
    __syncthreads();
    if ((threadIdx.x & 63) == 0) sc[wid] = v;
    __syncthreads();
    return sc[0] + sc[1] + sc[2] + sc[3];
}
DI float block_max256(float v, float* sc) {
    #pragma unroll
    for (int o = 32; o > 0; o >>= 1) v = fmaxf(v, __shfl_xor(v, o, 64));
    int wid = threadIdx.x >> 6;
    __syncthreads();
    if ((threadIdx.x & 63) == 0) sc[wid] = v;
    __syncthreads();
    return fmaxf(fmaxf(sc[0], sc[1]), fmaxf(sc[2], sc[3]));
}

// ---------------- adp = softmax(relu(nv1@nv2), axis=1), bf16 out ----------------
__global__ __launch_bounds__(256) void k_adp(const float* __restrict__ nv1,
                                             const float* __restrict__ nv2,
                                             ushort* __restrict__ adp) {
    __shared__ float r[6];
    __shared__ float sc[4];
    int row = blockIdx.x, tid = threadIdx.x;
    if (tid < 6) r[tid] = nv1[row * 6 + tid];
    __syncthreads();
    float e[4];
    #pragma unroll
    for (int q = 0; q < 4; q++) {
        int j = tid + q * 256;
        float s = 0.f;
        #pragma unroll
        for (int k = 0; k < 6; k++) s += r[k] * nv2[k * 1024 + j];
        e[q] = s > 0.f ? s : 0.f;
    }
    float m = fmaxf(fmaxf(e[0], e[1]), fmaxf(e[2], e[3]));
    m = block_max256(m, sc);
    float ps = 0.f;
    #pragma unroll
    for (int q = 0; q < 4; q++) { e[q] = __expf(e[q] - m); ps += e[q]; }
    ps = block_sum256(ps, sc);
    float rinv = 1.f / ps;
    #pragma unroll
    for (int q = 0; q < 4; q++) adp[(long)row * 1024 + tid + q * 256] = f2b(e[q] * rinv);
}

// ------- transpose in: x[b][c][n][l] -> Xb[(b*12+l)][n][c] bf16 + fp32 copy -------
__global__ __launch_bounds__(256) void k_tin(const float* __restrict__ x,
                                             ushort* __restrict__ xb,
                                             float* __restrict__ xf) {
    __shared__ float t[64][65];
    int nl0 = blockIdx.x * 64, c0 = blockIdx.y * 64, b = blockIdx.z;
    int lx = threadIdx.x & 63, ly = threadIdx.x >> 6;
    #pragma unroll
    for (int i = 0; i < 16; i++) {
        int c = c0 + ly + i * 4;
        t[ly + i * 4][lx] = x[(long)(b * 256 + c) * 12288 + nl0 + lx];
    }
    __syncthreads();
    #pragma unroll
    for (int i = 0; i < 16; i++) {
        int nl = nl0 + ly + i * 4;
        int n = nl / 12, l = nl % 12;
        long idx = ((long)(b * 12 + l) * 1024 + n) * 256 + c0 + lx;
        float v = t[lx][ly + i * 4];
        xb[idx] = f2b(v);
        xf[idx] = v;
    }
}

// ---------------- per-bl transpose Xb[n][c] -> XTT[c][n] (bf16) ----------------
__global__ __launch_bounds__(256) void k_xtt(const ushort* __restrict__ X,
                                             ushort* __restrict__ XT) {
    __shared__ ushort t[64][68];
    int bl = blockIdx.z;
    int n0 = blockIdx.x * 64, c0 = blockIdx.y * 64;
    int lx = threadIdx.x & 63, ly = threadIdx.x >> 6;
    const ushort* Xp = X + (long)bl * SLAB;
    #pragma unroll
    for (int i = 0; i < 16; i++)
        t[ly + i * 4][lx] = Xp[(long)(n0 + ly + i * 4) * 256 + c0 + lx];
    __syncthreads();
    ushort* Tp = XT + (long)bl * SLAB;
    #pragma unroll
    for (int i = 0; i < 16; i++)
        Tp[(long)(c0 + ly + i * 4) * 1024 + n0 + lx] = t[lx][ly + i * 4];
}

// -------- GAT weight transposes 256x256 fp32 [c][o] -> bf16 [o][c] --------
__global__ __launch_bounds__(256) void k_wt2(const float* __restrict__ S0, ushort* __restrict__ D0,
                                             const float* __restrict__ S1, ushort* __restrict__ D1) {
    __shared__ float t[64][65];
    const float* S = blockIdx.z ? S1 : S0;
    ushort* D = blockIdx.z ? D1 : D0;
    int c0 = blockIdx.x * 64, o0 = blockIdx.y * 64;
    int lx = threadIdx.x & 63, ly = threadIdx.x >> 6;
    #pragma unroll
    for (int i = 0; i < 16; i++)
        t[ly + i * 4][lx] = S[(long)(c0 + ly + i * 4) * 256 + o0 + lx];
    __syncthreads();
    #pragma unroll
    for (int i = 0; i < 16; i++)
        D[(long)(o0 + ly + i * 4) * 256 + c0 + lx] = f2b(t[lx][ly + i * 4]);
}

// ---------------- fp32 -> bf16 straight cast ----------------
__global__ __launch_bounds__(256) void k_wconv(const float* __restrict__ S, ushort* __restrict__ D) {
    long i = (long)blockIdx.x * 256 + threadIdx.x;
    D[i] = f2b(S[i]);
}

// ----- va = W @ a pair: va[c]=sum_o W[c][o]a[o], va[256+c]= with a[256+o] -----
__global__ __launch_bounds__(256) void k_va(const float* __restrict__ W, const float* __restrict__ a,
                                            float* __restrict__ va) {
    __shared__ float sc[4];
    int c = blockIdx.x, t = threadIdx.x;
    float w = W[(long)c * 256 + t];
    float s1 = block_sum256(w * a[t], sc);
    float s2 = block_sum256(w * a[256 + t], sc);
    if (t == 0) { va[c] = s1; va[256 + c] = s2; }
}

// ------- weight/bias prep: wt[n][c] = w[c][n]+1, bt[n][c] = b[c][n] -------
__global__ __launch_bounds__(256) void k_wtprep(const float* __restrict__ w,
                                                const float* __restrict__ b,
                                                float* __restrict__ wt,
                                                float* __restrict__ bt) {
    int n = blockIdx.x, c = threadIdx.x;
    wt[(long)n * 256 + c] = w[(long)c * 1024 + n] + 1.f;
    bt[(long)n * 256 + c] = b[(long)c * 1024 + n];
}

// ------- pack mask bits: maskw[row][w] bit b = dg[row][w*32+b] > 0 -------
__global__ __launch_bounds__(256) void k_maskpack(const int* __restrict__ dg,
                                                  uint* __restrict__ maskw) {
    int w = blockIdx.x * 256 + threadIdx.x;     // 32768 words
    int row = w >> 5, wo = w & 31;
    uint m = 0;
    #pragma unroll
    for (int b = 0; b < 32; b++)
        m |= (dg[(long)row * 1024 + wo * 32 + b] > 0 ? 1u : 0u) << b;
    maskw[w] = m;
}

// ---------------- bf16 MFMA GEMM: C[m][n] = sum_k A[m][k] * Bt[n][k] (+bias[n]) ----
// 128x128 tile, BK=32, 4 waves 2x2, 16x16x32 mfma. M=gridDim.x*128, N=gridDim.y*128.
template<int NPAIR>
__global__ __launch_bounds__(256) void k_bgemm(
    const ushort* __restrict__ A0, long sA0,
    const ushort* __restrict__ A1, long sA1,
    int lda, int K0, int KK,
    const ushort* __restrict__ Bt, long sBt,
    const float* __restrict__ bias,
    float* __restrict__ Cf, ushort* __restrict__ Cb, long sC) {
    __shared__ ushort As[128 * 32];
    __shared__ ushort Bs[128 * 32];
    const int tid = threadIdx.x;
    const int bl = blockIdx.z;
    const int m0 = blockIdx.x * 128, n0 = blockIdx.y * 128;
    const int N = gridDim.y * 128;
    const int lane = tid & 63, w = tid >> 6;
    const int wm = (w >> 1) * 64, wn = (w & 1) * 64;
    const int sr = tid >> 2, sk = (tid & 3) * 8;
    const int fr = lane & 15, fk = (lane >> 4) * 8;
    f32x4 acc[4][4] = {};
    const ushort* Ab0 = A0 + (long)bl * sA0;
    const ushort* Ab1 = (NPAIR == 2) ? A1 + (long)bl * sA1 : nullptr;
    const ushort* Bb = Bt + (long)bl * sBt;
    for (int k0 = 0; k0 < KK; k0 += 32) {
        const ushort* Asrc = Ab0; int kl = k0;
        if (NPAIR == 2 && k0 >= K0) { Asrc = Ab1; kl = k0 - K0; }
        __syncthreads();
        *(uint4*)&As[sr * 32 + sk]        = *(const uint4*)&Asrc[(long)(m0 + sr) * lda + kl + sk];
        *(uint4*)&As[(sr + 64) * 32 + sk] = *(const uint4*)&Asrc[(long)(m0 + sr + 64) * lda + kl + sk];
        *(uint4*)&Bs[sr * 32 + sk]        = *(const uint4*)&Bb[(long)(n0 + sr) * KK + k0 + sk];
        *(uint4*)&Bs[(sr + 64) * 32 + sk] = *(const uint4*)&Bb[(long)(n0 + sr + 64) * KK + k0 + sk];
        __syncthreads();
        bf16x8 af[4], bg[4];
        #pragma unroll
        for (int i = 0; i < 4; i++) {
            af[i] = *(const bf16x8*)&As[(wm + i * 16 + fr) * 32 + fk];
            bg[i] = *(const bf16x8*)&Bs[(wn + i * 16 + fr) * 32 + fk];
        }
        #pragma unroll
        for (int i = 0; i < 4; i++)
            #pragma unroll
            for (int j = 0; j < 4; j++)
                acc[i][j] = __builtin_amdgcn_mfma_f32_16x16x32_bf16(af[i], bg[j], acc[i][j], 0, 0, 0);
    }
    const int cn = lane & 15, rb = (lane >> 4) * 4;
    #pragma unroll
    for (int j = 0; j < 4; j++) {
        int n = n0 + wn + j * 16 + cn;
        float bv = bias ? bias[n] : 0.f;
        #pragma unroll
        for (int i = 0; i < 4; i++) {
            #pragma unroll
            for (int r = 0; r < 4; r++) {
                int m = m0 + wm + i * 16 + rb + r;
                float v = acc[i][j][r] + bv;
                long idx = (long)bl * sC + (long)m * N + n;
                if (Cf) Cf[idx] = v;
                if (Cb) Cb[idx] = f2b(v);
            }
        }
    }
}

// ---------------- w1/w2 GEMV: o[row] = X[row,:].va ----------------
__global__ __launch_bounds__(256) void k_dots(const ushort* __restrict__ X,
                                              const float* __restrict__ va,
                                              float* __restrict__ o1,
                                              float* __restrict__ o2) {
    int wid = threadIdx.x >> 6, lane = threadIdx.x & 63;
    long row = (long)blockIdx.x * 4 + wid;
    uint2 xv = *(const uint2*)(X + row * 256 + lane * 4);
    float x0 = b2f(xv.x), x1 = b2f(xv.x >> 16), x2 = b2f(xv.y), x3 = b2f(xv.y >> 16);
    float4 v1 = *(const float4*)&va[lane * 4];
    float4 v2 = *(const float4*)&va[256 + lane * 4];
    float s1 = x0 * v1.x + x1 * v1.y + x2 * v1.z + x3 * v1.w;
    float s2 = x0 * v2.x + x1 * v2.y + x2 * v2.z + x3 * v2.w;
    #pragma unroll
    for (int o = 32; o > 0; o >>= 1) { s1 += __shfl_xor(s1, o, 64); s2 += __shfl_xor(s2, o, 64); }
    if (lane == 0) { o1[row] = s1; o2[row] = s2; }
}

// ------- MFMA attention: rank-1 scores, masked softmax, P@Wh, elu -------
DI float attn_p(float w1, float w2, uint bit, float mr) {
    float e = w1 + w2;
    e = e > 0.f ? e : 0.2f * e;
    float p = __expf(e - mr);
    return bit ? p : 0.f;
}

__global__ __launch_bounds__(256) void k_attn_mf(
    const ushort* __restrict__ WhT,   // [48][256][1024] bf16
    const float* __restrict__ w1v, const float* __restrict__ w2v,
    const uint* __restrict__ maskw,   // [1024][32]
    float* __restrict__ outF, ushort* __restrict__ outB) {
    __shared__ ushort P[32 * 256];    // 16KB, swizzled
    __shared__ float w2s[1024];
    __shared__ float w1s[32];
    __shared__ uint msk[1024];        // [row][word]
    __shared__ float pmax[32 * 8];
    __shared__ float psum[32 * 8];
    __shared__ float mrow[32];
    __shared__ float ssum[32];
    __shared__ float rsv[32];
    int d = blockIdx.x;
    int lidx = (d & 7) * 192 + (d >> 3);     // XCD-chunked: each XCD gets 6 whole bls
    int bl = lidx >> 5;
    int i0 = (lidx & 31) * 32;
    int tid = threadIdx.x;
    #pragma unroll
    for (int q = 0; q < 4; q++) {
        int k = tid + q * 256;
        w2s[k] = w2v[(long)bl * 1024 + k];
        msk[k] = maskw[(long)(i0 + (k >> 5)) * 32 + (k & 31)];
    }
    if (tid < 32) w1s[tid] = w1v[(long)bl * 1024 + i0 + tid];
    __syncthreads();
    // pass 1: per-row masked max of w2 (leaky is monotone, so m = f(w1 + max w2))
    int row = tid >> 3, jt = tid & 7;
    float mloc = -1e30f;
    #pragma unroll
    for (int wq = 0; wq < 4; wq++) {
        uint mw = msk[row * 32 + jt * 4 + wq];
        int jb = jt * 128 + wq * 32;
        #pragma unroll
        for (int b = 0; b < 32; b++)
            mloc = fmaxf(mloc, ((mw >> b) & 1) ? w2s[jb + b] : -1e30f);
    }
    pmax[row * 8 + jt] = mloc;
    __syncthreads();
    if (tid < 32) {
        float m = pmax[tid * 8];
        #pragma unroll
        for (int t = 1; t < 8; t++) m = fmaxf(m, pmax[tid * 8 + t]);
        float e = w1s[tid] + m;
        mrow[tid] = (e > 0.f) ? e : 0.2f * e;
        ssum[tid] = 0.f;
    }
    __syncthreads();
    const float w1r = w1s[row];
    const int lane = tid & 63, w = tid >> 6;
    const int wn = w * 64;
    const int fr = lane & 15, fk8 = (lane >> 4) * 8;
    f32x4 acc[2][4] = {};
    const ushort* bp = WhT + (long)bl * SLAB;
    for (int jc = 0; jc < 4; jc++) {
        int j0 = jc * 256;
        {   // P chunk
            float mr = mrow[row];
            uint mw = msk[row * 32 + jc * 8 + jt];
            int jb = j0 + jt * 32;
            float sloc = 0.f;
            uint swz = (row & 7) << 4;
            char* pbase = (char*)P + row * 512;
            #pragma unroll
            for (int g = 0; g < 4; g++) {
                uint mg = mw >> (g * 8);
                int jg = jb + g * 8;
                float p0 = attn_p(w1r, w2s[jg + 0], mg & 1, mr);
                float p1 = attn_p(w1r, w2s[jg + 1], (mg >> 1) & 1, mr);
                float p2 = attn_p(w1r, w2s[jg + 2], (mg >> 2) & 1, mr);
                float p3 = attn_p(w1r, w2s[jg + 3], (mg >> 3) & 1, mr);
                float p4 = attn_p(w1r, w2s[jg + 4], (mg >> 4) & 1, mr);
                float p5 = attn_p(w1r, w2s[jg + 5], (mg >> 5) & 1, mr);
                float p6 = attn_p(w1r, w2s[jg + 6], (mg >> 6) & 1, mr);
                float p7 = attn_p(w1r, w2s[jg + 7], (mg >> 7) & 1, mr);
                sloc += p0 + p1 + p2 + p3 + p4 + p5 + p6 + p7;
                uint4 pv;
                pv.x = (uint)f2b(p0) | ((uint)f2b(p1) << 16);
                pv.y = (uint)f2b(p2) | ((uint)f2b(p3) << 16);
                pv.z = (uint)f2b(p4) | ((uint)f2b(p5) << 16);
                pv.w = (uint)f2b(p6) | ((uint)f2b(p7) << 16);
                *(uint4*)(pbase + (((jt * 64 + g * 16)) ^ swz)) = pv;
            }
            psum[row * 8 + jt] = sloc;
        }
        __syncthreads();
        if (tid < 32) {
            float s = 0.f;
            #pragma unroll
            for (int t = 0; t < 8; t++) s += psum[tid * 8 + t];
            ssum[tid] += s;
        }
        #pragma unroll
        for (int ks = 0; ks < 8; ks++) {
            int kb = ks * 32 + fk8;
            bf16x8 af[2], bg[4];
            #pragma unroll
            for (int mt = 0; mt < 2; mt++) {
                int r = mt * 16 + fr;
                af[mt] = *(const bf16x8*)((char*)P + r * 512 + ((kb * 2) ^ ((r & 7) << 4)));
            }
            #pragma unroll
            for (int nt = 0; nt < 4; nt++) {
                int c = wn + nt * 16 + fr;
                bg[nt] = *(const bf16x8*)&bp[(long)c * 1024 + j0 + kb];
            }
            #pragma unroll
            for (int mt = 0; mt < 2; mt++)
                #pragma unroll
                for (int nt = 0; nt < 4; nt++)
                    acc[mt][nt] = __builtin_amdgcn_mfma_f32_16x16x32_bf16(af[mt], bg[nt], acc[mt][nt], 0, 0, 0);
        }
        __syncthreads();
    }
    if (tid < 32) rsv[tid] = 1.f / ssum[tid];
    __syncthreads();
    #pragma unroll
    for (int mt = 0; mt < 2; mt++) {
        #pragma unroll
        for (int r = 0; r < 4; r++) {
            int i = mt * 16 + (lane >> 4) * 4 + r;
            float sc = rsv[i];
            #pragma unroll
            for (int nt = 0; nt < 4; nt++) {
                int c = wn + nt * 16 + fr;
                float v = acc[mt][nt][r] * sc;
                v = (v > 0.f) ? v : __expf(v) - 1.f;       // elu
                long idx = (long)bl * SLAB + (long)(i0 + i) * 256 + c;
                if (outF) outF[idx] = v;
                if (outB) outB[idx] = f2b(v);
            }
        }
    }
}

// ------- fuse: a_s*gat(bf16) + (1-a_s)*gcn(f32) + x_in(f32) -------
__global__ __launch_bounds__(256) void k_fuse(const ushort* __restrict__ gat,
                                              const float4* __restrict__ gcn,
                                              const float4* __restrict__ xf,
                                              const float* __restrict__ alpha,
                                              float4* __restrict__ o) {
    long i = (long)blockIdx.x * 256 + threadIdx.x;
    float as = 1.f / (1.f + __expf(-alpha[0]));
    float bs = 1.f - as;
    uint2 hv = ((const uint2*)gat)[i];
    float4 g = gcn[i], x = xf[i];
    o[i] = make_float4(as * b2f(hv.x) + bs * g.x + x.x,
                       as * b2f(hv.x >> 16) + bs * g.y + x.y,
                       as * b2f(hv.y) + bs * g.z + x.z,
                       as * b2f(hv.y >> 16) + bs * g.w + x.w);
}

// ---------------- layernorm over each 262144-slab ----------------
__global__ __launch_bounds__(256) void k_ln_part(const float* __restrict__ x,
                                                 float2* __restrict__ part) {
    __shared__ float sc[4];
    int bl = blockIdx.y;
    const float4* p = (const float4*)(x + (long)bl * SLAB + (long)blockIdx.x * 4096);
    float s = 0.f, q = 0.f;
    #pragma unroll
    for (int i = 0; i < 4; i++) {
        float4 v = p[i * 256 + threadIdx.x];
        s += v.x + v.y + v.z + v.w;
        q += v.x * v.x + v.y * v.y + v.z * v.z + v.w * v.w;
    }
    s = block_sum256(s, sc);
    q = block_sum256(q, sc);
    if (threadIdx.x == 0) part[bl * 64 + blockIdx.x] = make_float2(s, q);
}

__global__ void k_ln_stats(const float2* __restrict__ part, float2* __restrict__ stats) {
    int bl = blockIdx.x;
    float2 v = part[bl * 64 + threadIdx.x];
    float s = v.x, q = v.y;
    #pragma unroll
    for (int o = 32; o > 0; o >>= 1) { s += __shfl_xor(s, o, 64); q += __shfl_xor(q, o, 64); }
    if (threadIdx.x == 0) {
        float mean = s / (float)SLAB;
        float var = q / (float)SLAB - mean * mean;
        stats[bl] = make_float2(mean, 1.f / sqrtf(var + 1e-5f));
    }
}

__global__ __launch_bounds__(256) void k_ln_apply(const float4* __restrict__ x,
                                                  const float2* __restrict__ stats,
                                                  float4* __restrict__ o,
                                                  ushort* __restrict__ ob) {
    long i = (long)blockIdx.x * 256 + threadIdx.x;
    int bl = (int)(i >> 16);
    float2 st = stats[bl];
    float4 v = x[i];
    float o0 = (v.x - st.x) * st.y, o1 = (v.y - st.x) * st.y;
    float o2 = (v.z - st.x) * st.y, o3 = (v.w - st.x) * st.y;
    o[i] = make_float4(o0, o1, o2, o3);
    uint2 ow;
    ow.x = (uint)f2b(o0) | ((uint)f2b(o1) << 16);
    ow.y = (uint)f2b(o2) | ((uint)f2b(o3) << 16);
    ((uint2*)ob)[i] = ow;
}

// ------- GLU elementwise: a *= sigmoid(c), also bf16 out -------
__global__ __launch_bounds__(256) void k_glumul(float4* __restrict__ a,
                                                const float4* __restrict__ c,
                                                ushort* __restrict__ ob) {
    long i = (long)blockIdx.x * 256 + threadIdx.x;
    float4 av = a[i], cv = c[i];
    av.x *= 1.f / (1.f + __expf(-cv.x));
    av.y *= 1.f / (1.f + __expf(-cv.y));
    av.z *= 1.f / (1.f + __expf(-cv.z));
    av.w *= 1.f / (1.f + __expf(-cv.w));
    a[i] = av;
    uint2 ow;
    ow.x = (uint)f2b(av.x) | ((uint)f2b(av.y) << 16);
    ow.y = (uint)f2b(av.z) | ((uint)f2b(av.w) << 16);
    ((uint2*)ob)[i] = ow;
}

// ------- final pre-LN: (glu + xn)*(1+w) + bias -------
__global__ __launch_bounds__(256) void k_finpre(const float4* __restrict__ glu,
                                                const float4* __restrict__ xn,
                                                const float4* __restrict__ wt,
                                                const float4* __restrict__ bt,
                                                float4* __restrict__ o) {
    long i = (long)blockIdx.x * 256 + threadIdx.x;
    long wi = i & 65535;
    float4 g = glu[i], x = xn[i], w = wt[wi], b = bt[wi];
    o[i] = make_float4((g.x + x.x) * w.x + b.x, (g.y + x.y) * w.y + b.y,
                       (g.z + x.z) * w.z + b.z, (g.w + x.w) * w.w + b.w);
}

// ------- final normalize + transpose back to [b][c][n][l] -------
__global__ __launch_bounds__(256) void k_out(const float* __restrict__ x,
                                             const float2* __restrict__ stats,
                                             float* __restrict__ out) {
    int n = blockIdx.x, b = blockIdx.y, c = threadIdx.x;
    float v[12];
    #pragma unroll
    for (int l = 0; l < 12; l++) {
        float2 st = stats[b * 12 + l];
        float t = x[(long)(b * 12 + l) * SLAB + (long)n * 256 + c];
        v[l] = (t - st.x) * st.y;
    }
    float4* op = (float4*)(out + ((long)(b * 256 + c) * 1024 + n) * 12);
    op[0] = make_float4(v[0], v[1], v[2], v[3]);
    op[1] = make_float4(v[4], v[5], v[6], v[7]);
    op[2] = make_float4(v[8], v[9], v[10], v[11]);
}

// =================================================================
extern "C" void kernel_launch(void* const* d_in, const int* in_sizes, int n_in,
                              void* d_out, int out_size, void* d_ws, size_t ws_size,
                              hipStream_t stream) {
    (void)in_sizes; (void)n_in; (void)out_size; (void)ws_size;
    const float* x_in = (const float*)d_in[0];
    const int*   dg   = (const int*)d_in[1];
    const float* nv1  = (const float*)d_in[2];
    const float* nv2  = (const float*)d_in[3];
    const float* Wmlp = (const float*)d_in[4];
    const float* bmlp = (const float*)d_in[5];
    const float* Wg0  = (const float*)d_in[6];
    const float* ag0  = (const float*)d_in[7];
    const float* Wgo  = (const float*)d_in[8];
    const float* ago  = (const float*)d_in[9];
    const float* Wg1  = (const float*)d_in[10];
    const float* bg1  = (const float*)d_in[11];
    const float* Wg2  = (const float*)d_in[12];
    const float* bg2  = (const float*)d_in[13];
    const float* Wg3  = (const float*)d_in[14];
    const float* bg3  = (const float*)d_in[15];
    const float* alpha = (const float*)d_in[16];
    const float* wgt  = (const float*)d_in[17];
    const float* bia  = (const float*)d_in[18];
    float* out = (float*)d_out;

    // ---- workspace plan (~207 MB; Af aliases the dead U1+U2 region) ----
    float* XTf = (float*)d_ws;          // fp32 x_in copy [bl][n][c]; later g2, glu_out
    float* Bf  = XTf + TOT;             // fp32 gcn; later xn
    ushort* U1 = (ushort*)(Bf + TOT);   // Xb bf16
    ushort* U2 = U1 + TOT;              // XTT; later g (attn1 out)
    float* Af  = (float*)U1;            // fp32, live only after U1/U2 dead
    ushort* U3 = U2 + TOT;              // x1b; later gat bf16; later xn bf16
    ushort* U4 = U3 + TOT;              // WhT; later glu-in bf16
    ushort* ADPB = U4 + TOT;            // [1024][1024]
    ushort* WMLPB = ADPB + (long)1024 * 1024;
    ushort* WG0T = WMLPB + 131072;
    ushort* WGOT = WG0T + 65536;
    ushort* WG1B = WGOT + 65536;
    ushort* WG2B = WG1B + 65536;
    ushort* WG3B = WG2B + 65536;
    float* VA = (float*)(WG3B + 65536);     // 1024 floats
    float* W1V = VA + 1024;
    float* W2V = W1V + 49152;
    uint* MASKW = (uint*)(W2V + 49152);     // 32768
    float2* PART = (float2*)(MASKW + 32768);
    float2* STATS = PART + 48 * 64;
    float* WT = (float*)(STATS + 48);
    float* BT2 = WT + SLAB;

    dim3 blk(256);
    // prep
    k_wt2<<<dim3(4, 4, 2), blk, 0, stream>>>(Wg0, WG0T, Wgo, WGOT);
    k_wconv<<<512, blk, 0, stream>>>(Wmlp, WMLPB);
    k_wconv<<<256, blk, 0, stream>>>(Wg1, WG1B);
    k_wconv<<<256, blk, 0, stream>>>(Wg2, WG2B);
    k_wconv<<<256, blk, 0, stream>>>(Wg3, WG3B);
    k_va<<<256, blk, 0, stream>>>(Wg0, ag0, VA);
    k_va<<<256, blk, 0, stream>>>(Wgo, ago, VA + 512);
    k_wtprep<<<1024, blk, 0, stream>>>(wgt, bia, WT, BT2);
    k_adp<<<1024, blk, 0, stream>>>(nv1, nv2, ADPB);
    k_maskpack<<<128, blk, 0, stream>>>(dg, MASKW);
    k_tin<<<dim3(192, 4, 4), blk, 0, stream>>>(x_in, U1, XTf);
    k_xtt<<<dim3(16, 4, 48), blk, 0, stream>>>(U1, U2);
    // x1 = adp @ x  (Bt = XTT) -> U3 bf16
    k_bgemm<1><<<dim3(8, 2, 48), blk, 0, stream>>>(ADPB, 0, nullptr, 0, 1024, 0, 1024,
                                                   U2, SLAB, nullptr, nullptr, U3, SLAB);
    // gcn = [x|x1] @ Wmlp(o,c) + b -> Bf fp32
    k_bgemm<2><<<dim3(8, 2, 48), blk, 0, stream>>>(U1, SLAB, U3, SLAB, 256, 256, 512,
                                                   WMLPB, 0, bmlp, Bf, nullptr, SLAB);
    // GAT layer 1
    k_dots<<<12288, blk, 0, stream>>>(U1, VA, W1V, W2V);
    k_bgemm<1><<<dim3(2, 8, 48), blk, 0, stream>>>(WG0T, 0, nullptr, 0, 256, 0, 256,
                                                   U1, SLAB, nullptr, nullptr, U4, SLAB);
    k_attn_mf<<<1536, blk, 0, stream>>>(U4, W1V, W2V, MASKW, nullptr, U2);
    // GAT layer 2
    k_dots<<<12288, blk, 0, stream>>>(U2, VA + 512, W1V, W2V);
    k_bgemm<1><<<dim3(2, 8, 48), blk, 0, stream>>>(WGOT, 0, nullptr, 0, 256, 0, 256,
                                                   U2, SLAB, nullptr, nullptr, U4, SLAB);
    k_attn_mf<<<1536, blk, 0, stream>>>(U4, W1V, W2V, MASKW, nullptr, U3);
    // fuse: gat(U3 bf16) + gcn(Bf) + x(XTf) -> Af
    k_fuse<<<12288, blk, 0, stream>>>(U3, (const float4*)Bf, (const float4*)XTf,
                                      alpha, (float4*)Af);
    // LN1: Af -> Bf fp32 + U3 bf16
    k_ln_part<<<dim3(64, 48), blk, 0, stream>>>(Af, PART);
    k_ln_stats<<<48, 64, 0, stream>>>(PART, STATS);
    k_ln_apply<<<12288, blk, 0, stream>>>((const float4*)Af, STATS, (float4*)Bf, U3);
    // GLU: g1 -> Af, g2 -> XTf   (Bt = Wg_i[o][c] row-major, NO transpose)
    k_bgemm<1><<<dim3(8, 2, 48), blk, 0, stream>>>(U3, SLAB, nullptr, 0, 256, 0, 256,
                                                   WG1B, 0, bg1, Af, nullptr, SLAB);
    k_bgemm<1><<<dim3(8, 2, 48), blk, 0, stream>>>(U3, SLAB, nullptr, 0, 256, 0, 256,
                                                   WG2B, 0, bg2, XTf, nullptr, SLAB);
    k_glumul<<<12288, blk, 0, stream>>>((float4*)Af, (const float4*)XTf, U4);
    // glu_out = (g1*sig(g2)) @ Wg3 -> XTf
    k_bgemm<1><<<dim3(8, 2, 48), blk, 0, stream>>>(U4, SLAB, nullptr, 0, 256, 0, 256,
                                                   WG3B, 0, bg3, XTf, nullptr, SLAB);
    // (glu + xn)*(1+w) + bias -> Af
    k_finpre<<<12288, blk, 0, stream>>>((const float4*)XTf, (const float4*)Bf,
                                        (const float4*)WT, (const float4*)BT2, (float4*)Af);
    // LN2 + out
    k_ln_part<<<dim3(64, 48), blk, 0, stream>>>(Af, PART);
    k_ln_stats<<<48, 64, 0, stream>>>(PART, STATS);
    k_out<<<dim3(1024, 4), blk, 0, stream>>>(Af, STATS, out);
}

// Round 4
// 569.392 us; speedup vs baseline: 4.0471x; 1.1626x over previous
//
#include <hip/hip_runtime.h>
#include <math.h>

#define DI __device__ __forceinline__
#define AS1 __attribute__((address_space(1)))
#define AS3 __attribute__((address_space(3)))

static constexpr int  B_ = 4, C_ = 256, N_ = 1024, L_ = 12, BL_ = 48;
static constexpr long SLAB = (long)N_ * C_;          // 262144 elems per (b,l)
static constexpr long TOT  = (long)BL_ * SLAB;       // 12,582,912 elems

typedef __attribute__((ext_vector_type(8))) short bf16x8;
typedef __attribute__((ext_vector_type(4))) float f32x4;

DI float b2f(uint hw) { return __builtin_bit_cast(float, (hw & 0xffffu) << 16); }
DI ushort f2b(float f) {
    uint u = __builtin_bit_cast(uint, f);
    u += 0x7FFFu + ((u >> 16) & 1u);
    return (ushort)(u >> 16);
}

DI void gload16(const void* g, void* l) {
    __builtin_amdgcn_global_load_lds((AS1 uint*)g, (AS3 uint*)l, 16, 0, 0);
}

// ---------------- block reductions (256 threads, 4 waves) ----------------
DI float block_sum256(float v, float* sc) {
    #pragma unroll
    for (int o = 32; o > 0; o >>= 1) v += __shfl_xor(v, o, 64);
    int wid = threadIdx.x >> 6;
    __syncthreads();
    if ((threadIdx.x & 63) == 0) sc[wid] = v;
    __syncthreads();
    return sc[0] + sc[1] + sc[2] + sc[3];
}
DI float block_max256(float v, float* sc) {
    #pragma unroll
    for (int o = 32; o > 0; o >>= 1) v = fmaxf(v, __shfl_xor(v, o, 64));
    int wid = threadIdx.x >> 6;
    __syncthreads();
    if ((threadIdx.x & 63) == 0) sc[wid] = v;
    __syncthreads();
    return fmaxf(fmaxf(sc[0], sc[1]), fmaxf(sc[2], sc[3]));
}

// ---------------- adp = softmax(relu(nv1@nv2), axis=1), bf16 out ----------------
__global__ __launch_bounds__(256) void k_adp(const float* __restrict__ nv1,
                                             const float* __restrict__ nv2,
                                             ushort* __restrict__ adp) {
    __shared__ float r[6];
    __shared__ float sc[4];
    int row = blockIdx.x, tid = threadIdx.x;
    if (tid < 6) r[tid] = nv1[row * 6 + tid];
    __syncthreads();
    float e[4];
    #pragma unroll
    for (int q = 0; q < 4; q++) {
        int j = tid + q * 256;
        float s = 0.f;
        #pragma unroll
        for (int k = 0; k < 6; k++) s += r[k] * nv2[k * 1024 + j];
        e[q] = s > 0.f ? s : 0.f;
    }
    float m = fmaxf(fmaxf(e[0], e[1]), fmaxf(e[2], e[3]));
    m = block_max256(m, sc);
    float ps = 0.f;
    #pragma unroll
    for (int q = 0; q < 4; q++) { e[q] = __expf(e[q] - m); ps += e[q]; }
    ps = block_sum256(ps, sc);
    float rinv = 1.f / ps;
    #pragma unroll
    for (int q = 0; q < 4; q++) adp[(long)row * 1024 + tid + q * 256] = f2b(e[q] * rinv);
}

// ------- transpose in: x[b][c][n][l] -> Xb[(b*12+l)][n][c] bf16 + fp32 copy -------
__global__ __launch_bounds__(256) void k_tin(const float* __restrict__ x,
                                             ushort* __restrict__ xb,
                                             float* __restrict__ xf) {
    __shared__ float t[64][65];
    int nl0 = blockIdx.x * 64, c0 = blockIdx.y * 64, b = blockIdx.z;
    int lx = threadIdx.x & 63, ly = threadIdx.x >> 6;
    #pragma unroll
    for (int i = 0; i < 16; i++) {
        int c = c0 + ly + i * 4;
        t[ly + i * 4][lx] = x[(long)(b * 256 + c) * 12288 + nl0 + lx];
    }
    __syncthreads();
    #pragma unroll
    for (int i = 0; i < 16; i++) {
        int nl = nl0 + ly + i * 4;
        int n = nl / 12, l = nl % 12;
        long idx = ((long)(b * 12 + l) * 1024 + n) * 256 + c0 + lx;
        float v = t[lx][ly + i * 4];
        xb[idx] = f2b(v);
        xf[idx] = v;
    }
}

// ---------------- per-bl transpose Xb[n][c] -> XTT[c][n] (bf16) ----------------
__global__ __launch_bounds__(256) void k_xtt(const ushort* __restrict__ X,
                                             ushort* __restrict__ XT) {
    __shared__ ushort t[64][68];
    int bl = blockIdx.z;
    int n0 = blockIdx.x * 64, c0 = blockIdx.y * 64;
    int lx = threadIdx.x & 63, ly = threadIdx.x >> 6;
    const ushort* Xp = X + (long)bl * SLAB;
    #pragma unroll
    for (int i = 0; i < 16; i++)
        t[ly + i * 4][lx] = Xp[(long)(n0 + ly + i * 4) * 256 + c0 + lx];
    __syncthreads();
    ushort* Tp = XT + (long)bl * SLAB;
    #pragma unroll
    for (int i = 0; i < 16; i++)
        Tp[(long)(c0 + ly + i * 4) * 1024 + n0 + lx] = t[lx][ly + i * 4];
}

// -------- GAT weight transposes 256x256 fp32 [c][o] -> bf16 [o][c] --------
__global__ __launch_bounds__(256) void k_wt2(const float* __restrict__ S0, ushort* __restrict__ D0,
                                             const float* __restrict__ S1, ushort* __restrict__ D1) {
    __shared__ float t[64][65];
    const float* S = blockIdx.z ? S1 : S0;
    ushort* D = blockIdx.z ? D1 : D0;
    int c0 = blockIdx.x * 64, o0 = blockIdx.y * 64;
    int lx = threadIdx.x & 63, ly = threadIdx.x >> 6;
    #pragma unroll
    for (int i = 0; i < 16; i++)
        t[ly + i * 4][lx] = S[(long)(c0 + ly + i * 4) * 256 + o0 + lx];
    __syncthreads();
    #pragma unroll
    for (int i = 0; i < 16; i++)
        D[(long)(o0 + ly + i * 4) * 256 + c0 + lx] = f2b(t[lx][ly + i * 4]);
}

// ---------------- fp32 -> bf16 straight cast ----------------
__global__ __launch_bounds__(256) void k_wconv(const float* __restrict__ S, ushort* __restrict__ D) {
    long i = (long)blockIdx.x * 256 + threadIdx.x;
    D[i] = f2b(S[i]);
}

// ------- interleaved GLU weights: WGI[p*32+q] = (q<16 ? Wg1 : Wg2) row p*16+q%16 -------
__global__ __launch_bounds__(256) void k_wgi(const float* __restrict__ W1, const float* __restrict__ b1,
                                             const float* __restrict__ W2, const float* __restrict__ b2,
                                             ushort* __restrict__ WGI, float* __restrict__ BI) {
    int n = blockIdx.x, p = n >> 5, q = n & 31;
    const float* src = (q < 16) ? W1 + (long)(p * 16 + q) * 256
                                : W2 + (long)(p * 16 + q - 16) * 256;
    WGI[(long)n * 256 + threadIdx.x] = f2b(src[threadIdx.x]);
    if (threadIdx.x == 0) BI[n] = (q < 16) ? b1[p * 16 + q] : b2[p * 16 + q - 16];
}

// ----- va = W @ a pair -----
__global__ __launch_bounds__(256) void k_va(const float* __restrict__ W, const float* __restrict__ a,
                                            float* __restrict__ va) {
    __shared__ float sc[4];
    int c = blockIdx.x, t = threadIdx.x;
    float w = W[(long)c * 256 + t];
    float s1 = block_sum256(w * a[t], sc);
    float s2 = block_sum256(w * a[256 + t], sc);
    if (t == 0) { va[c] = s1; va[256 + c] = s2; }
}

// ------- weight/bias prep: wt[n][c] = w[c][n]+1, bt[n][c] = b[c][n] -------
__global__ __launch_bounds__(256) void k_wtprep(const float* __restrict__ w,
                                                const float* __restrict__ b,
                                                float* __restrict__ wt,
                                                float* __restrict__ bt) {
    int n = blockIdx.x, c = threadIdx.x;
    wt[(long)n * 256 + c] = w[(long)c * 1024 + n] + 1.f;
    bt[(long)n * 256 + c] = b[(long)c * 1024 + n];
}

// ------- pack mask bits -------
__global__ __launch_bounds__(256) void k_maskpack(const int* __restrict__ dg,
                                                  uint* __restrict__ maskw) {
    int w = blockIdx.x * 256 + threadIdx.x;
    int row = w >> 5, wo = w & 31;
    uint m = 0;
    #pragma unroll
    for (int b = 0; b < 32; b++)
        m |= (dg[(long)row * 1024 + wo * 32 + b] > 0 ? 1u : 0u) << b;
    maskw[w] = m;
}

// ------- bf16 MFMA GEMM: C[m][n] = sum_k A[m][k] * Bt[n][k] (+bias[n]) -------
// 128x128 tile, BK=32, 4 waves 2x2, global_load_lds staging.
// GLU=1: Bt is 16-col-interleaved [g1|g2] pairs; epilogue writes h=g1*sig(g2) bf16 [m][256].
template<int NPAIR, int GLU>
__global__ __launch_bounds__(256) void k_bgemm(
    const ushort* __restrict__ A0, long sA0,
    const ushort* __restrict__ A1, long sA1,
    int lda, int K0, int KK,
    const ushort* __restrict__ Bt, long sBt,
    const float* __restrict__ bias,
    float* __restrict__ Cf, ushort* __restrict__ Cb, long sC,
    const float* __restrict__ biasi) {
    __shared__ ushort As[128 * 32];
    __shared__ ushort Bs[128 * 32];
    const int tid = threadIdx.x;
    const int bl = blockIdx.z;
    const int m0 = blockIdx.x * 128, n0 = blockIdx.y * 128;
    const int N = gridDim.y * 128;
    const int lane = tid & 63, w = tid >> 6;
    const int wm = (w >> 1) * 64, wn = (w & 1) * 64;
    const int sr = tid >> 2, sk = (tid & 3) * 8;
    const int fr = lane & 15, fk = (lane >> 4) * 8;
    f32x4 acc[4][4] = {};
    const ushort* Ab0 = A0 + (long)bl * sA0;
    const ushort* Ab1 = (NPAIR == 2) ? A1 + (long)bl * sA1 : nullptr;
    const ushort* Bb = Bt + (long)bl * sBt;
    for (int k0 = 0; k0 < KK; k0 += 32) {
        const ushort* Asrc = Ab0; int kl = k0;
        if (NPAIR == 2 && k0 >= K0) { Asrc = Ab1; kl = k0 - K0; }
        __syncthreads();
        gload16(&Asrc[(long)(m0 + sr) * lda + kl + sk],      &As[sr * 32 + sk]);
        gload16(&Asrc[(long)(m0 + sr + 64) * lda + kl + sk], &As[(sr + 64) * 32 + sk]);
        gload16(&Bb[(long)(n0 + sr) * KK + k0 + sk],         &Bs[sr * 32 + sk]);
        gload16(&Bb[(long)(n0 + sr + 64) * KK + k0 + sk],    &Bs[(sr + 64) * 32 + sk]);
        __syncthreads();
        bf16x8 af[4], bg[4];
        #pragma unroll
        for (int i = 0; i < 4; i++) {
            af[i] = *(const bf16x8*)&As[(wm + i * 16 + fr) * 32 + fk];
            bg[i] = *(const bf16x8*)&Bs[(wn + i * 16 + fr) * 32 + fk];
        }
        #pragma unroll
        for (int i = 0; i < 4; i++)
            #pragma unroll
            for (int j = 0; j < 4; j++)
                acc[i][j] = __builtin_amdgcn_mfma_f32_16x16x32_bf16(af[i], bg[j], acc[i][j], 0, 0, 0);
    }
    const int cn = lane & 15, rb = (lane >> 4) * 4;
    if (GLU) {
        #pragma unroll
        for (int nt = 0; nt < 4; nt += 2) {
            int n1 = n0 + wn + nt * 16 + cn;          // interleaved col (g1 half)
            int hcol = ((n1 >> 5) << 4) + cn;         // original col p*16+cn
            float b1 = biasi[n1], b2 = biasi[n1 + 16];
            #pragma unroll
            for (int i = 0; i < 4; i++) {
                #pragma unroll
                for (int r = 0; r < 4; r++) {
                    int m = m0 + wm + i * 16 + rb + r;
                    float g1 = acc[i][nt][r] + b1;
                    float g2 = acc[i][nt + 1][r] + b2;
                    float h = g1 / (1.f + __expf(-g2));
                    Cb[(long)bl * sC + (long)m * 256 + hcol] = f2b(h);
                }
            }
        }
    } else {
        #pragma unroll
        for (int j = 0; j < 4; j++) {
            int n = n0 + wn + j * 16 + cn;
            float bv = bias ? bias[n] : 0.f;
            #pragma unroll
            for (int i = 0; i < 4; i++) {
                #pragma unroll
                for (int r = 0; r < 4; r++) {
                    int m = m0 + wm + i * 16 + rb + r;
                    float v = acc[i][j][r] + bv;
                    long idx = (long)bl * sC + (long)m * N + n;
                    if (Cf) Cf[idx] = v;
                    if (Cb) Cb[idx] = f2b(v);
                }
            }
        }
    }
}

// ---------------- w1/w2 GEMV ----------------
__global__ __launch_bounds__(256) void k_dots(const ushort* __restrict__ X,
                                              const float* __restrict__ va,
                                              float* __restrict__ o1,
                                              float* __restrict__ o2) {
    int wid = threadIdx.x >> 6, lane = threadIdx.x & 63;
    long row = (long)blockIdx.x * 4 + wid;
    uint2 xv = *(const uint2*)(X + row * 256 + lane * 4);
    float x0 = b2f(xv.x), x1 = b2f(xv.x >> 16), x2 = b2f(xv.y), x3 = b2f(xv.y >> 16);
    float4 v1 = *(const float4*)&va[lane * 4];
    float4 v2 = *(const float4*)&va[256 + lane * 4];
    float s1 = x0 * v1.x + x1 * v1.y + x2 * v1.z + x3 * v1.w;
    float s2 = x0 * v2.x + x1 * v2.y + x2 * v2.z + x3 * v2.w;
    #pragma unroll
    for (int o = 32; o > 0; o >>= 1) { s1 += __shfl_xor(s1, o, 64); s2 += __shfl_xor(s2, o, 64); }
    if (lane == 0) { o1[row] = s1; o2[row] = s2; }
}

// ------- MFMA attention v2: 64 rows/block, conflict-free LDS, bg prefetch -------
DI float attn_p(float w1, float w2, uint bit, float mr) {
    float e = w1 + w2;
    e = e > 0.f ? e : 0.2f * e;
    float p = __expf(e - mr);
    return bit ? p : 0.f;
}

__global__ __launch_bounds__(256) void k_attn_mf(
    const ushort* __restrict__ WhT,   // [48][256][1024] bf16
    const float* __restrict__ w1v, const float* __restrict__ w2v,
    const uint* __restrict__ maskw,   // [1024][32]
    ushort* __restrict__ outB) {
    __shared__ ushort P2[32 * 64 * 8];   // [kq][row][8] 32 KB
    __shared__ float w2s[1024];
    __shared__ float w1s[64];
    __shared__ uint msk[64 * 33];        // padded stride 33
    __shared__ float pmax[4][64];
    __shared__ float psum[4][64];
    __shared__ float mrow[64];
    __shared__ float ssum[64];
    __shared__ float rsv[64];
    int d = blockIdx.x;                  // 768 blocks
    int lidx = (d & 7) * 96 + (d >> 3);  // XCD-chunked: 6 bl per XCD
    int bl = lidx >> 4;
    int i0 = (lidx & 15) * 64;
    int tid = threadIdx.x;
    #pragma unroll
    for (int q = 0; q < 4; q++) w2s[tid + q * 256] = w2v[(long)bl * 1024 + tid + q * 256];
    if (tid < 64) w1s[tid] = w1v[(long)bl * 1024 + i0 + tid];
    {   // mask load: 2048 words, coalesced, store at padded stride
        const uint4* gm = (const uint4*)(maskw + (long)i0 * 32);
        uint4 ma = gm[tid * 2], mb = gm[tid * 2 + 1];
        int r0 = tid >> 2, w0 = (tid & 3) * 8;
        uint* mp = &msk[r0 * 33 + w0];
        mp[0] = ma.x; mp[1] = ma.y; mp[2] = ma.z; mp[3] = ma.w;
        mp[4] = mb.x; mp[5] = mb.y; mp[6] = mb.z; mp[7] = mb.w;
    }
    __syncthreads();
    const int row = tid & 63, jt = tid >> 6;
    // pass 1: per-row masked max of w2 over this thread's 256-j strip
    float mloc = -1e30f;
    #pragma unroll
    for (int wq = 0; wq < 8; wq++) {
        uint mw = msk[row * 33 + jt * 8 + wq];
        int jb = jt * 256 + wq * 32;
        #pragma unroll
        for (int b = 0; b < 32; b++)
            mloc = fmaxf(mloc, ((mw >> b) & 1) ? w2s[jb + b] : -1e30f);
    }
    pmax[jt][row] = mloc;
    __syncthreads();
    if (tid < 64) {
        float m = fmaxf(fmaxf(pmax[0][tid], pmax[1][tid]), fmaxf(pmax[2][tid], pmax[3][tid]));
        float e = w1s[tid] + m;
        mrow[tid] = (e > 0.f) ? e : 0.2f * e;
        ssum[tid] = 0.f;
    }
    __syncthreads();
    const int lane = tid & 63, w = tid >> 6;
    const int wn = w * 64;
    const int fr = lane & 15, fk8 = (lane >> 4) * 8;
    f32x4 acc[4][4] = {};
    const ushort* bp = WhT + (long)bl * SLAB;
    const float w1r = w1s[row];
    const float mr = mrow[row];
    #pragma unroll 1
    for (int jc = 0; jc < 4; jc++) {
        int j0 = jc * 256;
        // prefetch bg for ks=0 of this chunk (independent of P)
        bf16x8 bgbuf[2][4];
        #pragma unroll
        for (int nt = 0; nt < 4; nt++)
            bgbuf[0][nt] = *(const bf16x8*)&bp[(long)(wn + nt * 16 + fr) * 1024 + j0 + fk8];
        // P-compute: thread covers rows=row, j = j0 + jt*64 + [0,64)
        uint mw0 = msk[row * 33 + jc * 8 + jt * 2];
        uint mw1 = msk[row * 33 + jc * 8 + jt * 2 + 1];
        float sloc = 0.f;
        #pragma unroll
        for (int u = 0; u < 8; u++) {
            uint mg = ((u & 4) ? mw1 : mw0) >> ((u & 3) * 8);
            int jb = j0 + jt * 64 + u * 8;
            float p0 = attn_p(w1r, w2s[jb + 0], mg & 1, mr);
            float p1 = attn_p(w1r, w2s[jb + 1], (mg >> 1) & 1, mr);
            float p2 = attn_p(w1r, w2s[jb + 2], (mg >> 2) & 1, mr);
            float p3 = attn_p(w1r, w2s[jb + 3], (mg >> 3) & 1, mr);
            float p4 = attn_p(w1r, w2s[jb + 4], (mg >> 4) & 1, mr);
            float p5 = attn_p(w1r, w2s[jb + 5], (mg >> 5) & 1, mr);
            float p6 = attn_p(w1r, w2s[jb + 6], (mg >> 6) & 1, mr);
            float p7 = attn_p(w1r, w2s[jb + 7], (mg >> 7) & 1, mr);
            sloc += p0 + p1 + p2 + p3 + p4 + p5 + p6 + p7;
            uint4 pv;
            pv.x = (uint)f2b(p0) | ((uint)f2b(p1) << 16);
            pv.y = (uint)f2b(p2) | ((uint)f2b(p3) << 16);
            pv.z = (uint)f2b(p4) | ((uint)f2b(p5) << 16);
            pv.w = (uint)f2b(p6) | ((uint)f2b(p7) << 16);
            int kq = jt * 8 + u;
            *(uint4*)((char*)P2 + (kq * 64 + row) * 16) = pv;   // wave-contiguous store
        }
        psum[jt][row] = sloc;
        __syncthreads();
        if (tid < 64)
            ssum[tid] += psum[0][tid] + psum[1][tid] + psum[2][tid] + psum[3][tid];
        // MFMA over chunk, bg double-buffered
        #pragma unroll
        for (int ks = 0; ks < 8; ks++) {
            if (ks < 7) {
                int kb = (ks + 1) * 32 + fk8;
                #pragma unroll
                for (int nt = 0; nt < 4; nt++)
                    bgbuf[(ks + 1) & 1][nt] =
                        *(const bf16x8*)&bp[(long)(wn + nt * 16 + fr) * 1024 + j0 + kb];
            }
            int kq = ks * 4 + (lane >> 4);
            bf16x8 af[4];
            #pragma unroll
            for (int mt = 0; mt < 4; mt++)
                af[mt] = *(const bf16x8*)((char*)P2 + (kq * 64 + mt * 16 + fr) * 16);
            #pragma unroll
            for (int mt = 0; mt < 4; mt++)
                #pragma unroll
                for (int nt = 0; nt < 4; nt++)
                    acc[mt][nt] = __builtin_amdgcn_mfma_f32_16x16x32_bf16(
                        af[mt], bgbuf[ks & 1][nt], acc[mt][nt], 0, 0, 0);
        }
        __syncthreads();
    }
    if (tid < 64) rsv[tid] = 1.f / ssum[tid];
    __syncthreads();
    #pragma unroll
    for (int mt = 0; mt < 4; mt++) {
        #pragma unroll
        for (int r = 0; r < 4; r++) {
            int i = mt * 16 + (lane >> 4) * 4 + r;
            float sc = rsv[i];
            #pragma unroll
            for (int nt = 0; nt < 4; nt++) {
                int c = wn + nt * 16 + fr;
                float v = acc[mt][nt][r] * sc;
                v = (v > 0.f) ? v : __expf(v) - 1.f;       // elu
                outB[(long)bl * SLAB + (long)(i0 + i) * 256 + c] = f2b(v);
            }
        }
    }
}

// ------- fuse: a_s*gat(bf16) + (1-a_s)*gcn(f32) + x_in(f32), + LN partials -------
__global__ __launch_bounds__(256) void k_fuse_ln(const ushort* __restrict__ gat,
                                                 const float4* __restrict__ gcn,
                                                 const float4* __restrict__ xf,
                                                 const float* __restrict__ alpha,
                                                 float4* __restrict__ o,
                                                 float2* __restrict__ part) {
    __shared__ float sc[4];
    int bl = blockIdx.y;
    long i = (long)bl * 65536 + blockIdx.x * 256 + threadIdx.x;
    float as = 1.f / (1.f + __expf(-alpha[0]));
    float bs = 1.f - as;
    uint2 hv = ((const uint2*)gat)[i];
    float4 g = gcn[i], x = xf[i];
    float4 v = make_float4(as * b2f(hv.x) + bs * g.x + x.x,
                           as * b2f(hv.x >> 16) + bs * g.y + x.y,
                           as * b2f(hv.y) + bs * g.z + x.z,
                           as * b2f(hv.y >> 16) + bs * g.w + x.w);
    o[i] = v;
    float s = v.x + v.y + v.z + v.w;
    float q = v.x * v.x + v.y * v.y + v.z * v.z + v.w * v.w;
    s = block_sum256(s, sc);
    q = block_sum256(q, sc);
    if (threadIdx.x == 0) part[bl * 256 + blockIdx.x] = make_float2(s, q);
}

// ------- stats from 256 partials per slab -------
__global__ __launch_bounds__(256) void k_stats256(const float2* __restrict__ part,
                                                  float2* __restrict__ stats) {
    __shared__ float sc[4];
    int bl = blockIdx.x;
    float2 v = part[bl * 256 + threadIdx.x];
    float s = block_sum256(v.x, sc);
    float q = block_sum256(v.y, sc);
    if (threadIdx.x == 0) {
        float mean = s / (float)SLAB;
        float var = q / (float)SLAB - mean * mean;
        stats[bl] = make_float2(mean, 1.f / sqrtf(var + 1e-5f));
    }
}

__global__ __launch_bounds__(256) void k_ln_apply(const float4* __restrict__ x,
                                                  const float2* __restrict__ stats,
                                                  float4* __restrict__ o,
                                                  ushort* __restrict__ ob) {
    long i = (long)blockIdx.x * 256 + threadIdx.x;
    int bl = (int)(i >> 16);
    float2 st = stats[bl];
    float4 v = x[i];
    float o0 = (v.x - st.x) * st.y, o1 = (v.y - st.x) * st.y;
    float o2 = (v.z - st.x) * st.y, o3 = (v.w - st.x) * st.y;
    o[i] = make_float4(o0, o1, o2, o3);
    uint2 ow;
    ow.x = (uint)f2b(o0) | ((uint)f2b(o1) << 16);
    ow.y = (uint)f2b(o2) | ((uint)f2b(o3) << 16);
    ((uint2*)ob)[i] = ow;
}

// ------- final pre-LN: (glu + xn)*(1+w) + bias, + LN partials -------
__global__ __launch_bounds__(256) void k_finpre_ln(const float4* __restrict__ glu,
                                                   const float4* __restrict__ xn,
                                                   const float4* __restrict__ wt,
                                                   const float4* __restrict__ bt,
                                                   float4* __restrict__ o,
                                                   float2* __restrict__ part) {
    __shared__ float sc[4];
    int bl = blockIdx.y;
    long i = (long)bl * 65536 + blockIdx.x * 256 + threadIdx.x;
    long wi = i & 65535;
    float4 g = glu[i], x = xn[i], w = wt[wi], b = bt[wi];
    float4 v = make_float4((g.x + x.x) * w.x + b.x, (g.y + x.y) * w.y + b.y,
                           (g.z + x.z) * w.z + b.z, (g.w + x.w) * w.w + b.w);
    o[i] = v;
    float s = v.x + v.y + v.z + v.w;
    float q = v.x * v.x + v.y * v.y + v.z * v.z + v.w * v.w;
    s = block_sum256(s, sc);
    q = block_sum256(q, sc);
    if (threadIdx.x == 0) part[bl * 256 + blockIdx.x] = make_float2(s, q);
}

// ------- final normalize + transpose back to [b][c][n][l] -------
__global__ __launch_bounds__(256) void k_out(const float* __restrict__ x,
                                             const float2* __restrict__ stats,
                                             float* __restrict__ out) {
    int n = blockIdx.x, b = blockIdx.y, c = threadIdx.x;
    float v[12];
    #pragma unroll
    for (int l = 0; l < 12; l++) {
        float2 st = stats[b * 12 + l];
        float t = x[(long)(b * 12 + l) * SLAB + (long)n * 256 + c];
        v[l] = (t - st.x) * st.y;
    }
    float4* op = (float4*)(out + ((long)(b * 256 + c) * 1024 + n) * 12);
    op[0] = make_float4(v[0], v[1], v[2], v[3]);
    op[1] = make_float4(v[4], v[5], v[6], v[7]);
    op[2] = make_float4(v[8], v[9], v[10], v[11]);
}

// =================================================================
extern "C" void kernel_launch(void* const* d_in, const int* in_sizes, int n_in,
                              void* d_out, int out_size, void* d_ws, size_t ws_size,
                              hipStream_t stream) {
    (void)in_sizes; (void)n_in; (void)out_size; (void)ws_size;
    const float* x_in = (const float*)d_in[0];
    const int*   dg   = (const int*)d_in[1];
    const float* nv1  = (const float*)d_in[2];
    const float* nv2  = (const float*)d_in[3];
    const float* Wmlp = (const float*)d_in[4];
    const float* bmlp = (const float*)d_in[5];
    const float* Wg0  = (const float*)d_in[6];
    const float* ag0  = (const float*)d_in[7];
    const float* Wgo  = (const float*)d_in[8];
    const float* ago  = (const float*)d_in[9];
    const float* Wg1  = (const float*)d_in[10];
    const float* bg1  = (const float*)d_in[11];
    const float* Wg2  = (const float*)d_in[12];
    const float* bg2  = (const float*)d_in[13];
    const float* Wg3  = (const float*)d_in[14];
    const float* bg3  = (const float*)d_in[15];
    const float* alpha = (const float*)d_in[16];
    const float* wgt  = (const float*)d_in[17];
    const float* bia  = (const float*)d_in[18];
    float* out = (float*)d_out;

    // ---- workspace (~208 MB; Af aliases the dead U1+U2 region) ----
    float* XTf = (float*)d_ws;          // fp32 x_in copy; later glu3 out
    float* Bf  = XTf + TOT;             // fp32 gcn; later xn
    ushort* U1 = (ushort*)(Bf + TOT);   // Xb bf16
    ushort* U2 = U1 + TOT;              // XTT; later g (attn1 out)
    float* Af  = (float*)U1;            // fp32, live only after U1/U2 dead
    ushort* U3 = U2 + TOT;              // x1b; later gat bf16; later xn bf16
    ushort* U4 = U3 + TOT;              // WhT; later h bf16
    ushort* ADPB = U4 + TOT;            // [1024][1024]
    ushort* WMLPB = ADPB + (long)1024 * 1024;
    ushort* WG0T = WMLPB + 131072;
    ushort* WGOT = WG0T + 65536;
    ushort* WGIB = WGOT + 65536;        // [512][256] interleaved g1/g2
    ushort* WG3B = WGIB + 131072;
    float* BIASI = (float*)(WG3B + 65536);  // 512
    float* VA = BIASI + 512;                // 1024
    float* W1V = VA + 1024;
    float* W2V = W1V + 49152;
    uint* MASKW = (uint*)(W2V + 49152);     // 32768
    float2* PART = (float2*)(MASKW + 32768); // [48][256]
    float2* STATS = PART + 48 * 256;
    float* WT = (float*)(STATS + 48);
    float* BT2 = WT + SLAB;

    dim3 blk(256);
    // prep
    k_wt2<<<dim3(4, 4, 2), blk, 0, stream>>>(Wg0, WG0T, Wgo, WGOT);
    k_wconv<<<512, blk, 0, stream>>>(Wmlp, WMLPB);
    k_wconv<<<256, blk, 0, stream>>>(Wg3, WG3B);
    k_wgi<<<512, blk, 0, stream>>>(Wg1, bg1, Wg2, bg2, WGIB, BIASI);
    k_va<<<256, blk, 0, stream>>>(Wg0, ag0, VA);
    k_va<<<256, blk, 0, stream>>>(Wgo, ago, VA + 512);
    k_wtprep<<<1024, blk, 0, stream>>>(wgt, bia, WT, BT2);
    k_adp<<<1024, blk, 0, stream>>>(nv1, nv2, ADPB);
    k_maskpack<<<128, blk, 0, stream>>>(dg, MASKW);
    k_tin<<<dim3(192, 4, 4), blk, 0, stream>>>(x_in, U1, XTf);
    k_xtt<<<dim3(16, 4, 48), blk, 0, stream>>>(U1, U2);
    // x1 = adp @ x  (Bt = XTT) -> U3 bf16
    k_bgemm<1, 0><<<dim3(8, 2, 48), blk, 0, stream>>>(ADPB, 0, nullptr, 0, 1024, 0, 1024,
                                                      U2, SLAB, nullptr, nullptr, U3, SLAB, nullptr);
    // gcn = [x|x1] @ Wmlp(o,c) + b -> Bf fp32
    k_bgemm<2, 0><<<dim3(8, 2, 48), blk, 0, stream>>>(U1, SLAB, U3, SLAB, 256, 256, 512,
                                                      WMLPB, 0, bmlp, Bf, nullptr, SLAB, nullptr);
    // GAT layer 1
    k_dots<<<12288, blk, 0, stream>>>(U1, VA, W1V, W2V);
    k_bgemm<1, 0><<<dim3(2, 8, 48), blk, 0, stream>>>(WG0T, 0, nullptr, 0, 256, 0, 256,
                                                      U1, SLAB, nullptr, nullptr, U4, SLAB, nullptr);
    k_attn_mf<<<768, blk, 0, stream>>>(U4, W1V, W2V, MASKW, U2);
    // GAT layer 2
    k_dots<<<12288, blk, 0, stream>>>(U2, VA + 512, W1V, W2V);
    k_bgemm<1, 0><<<dim3(2, 8, 48), blk, 0, stream>>>(WGOT, 0, nullptr, 0, 256, 0, 256,
                                                      U2, SLAB, nullptr, nullptr, U4, SLAB, nullptr);
    k_attn_mf<<<768, blk, 0, stream>>>(U4, W1V, W2V, MASKW, U3);
    // fuse + LN1 partials -> Af, PART
    k_fuse_ln<<<dim3(256, 48), blk, 0, stream>>>(U3, (const float4*)Bf, (const float4*)XTf,
                                                 alpha, (float4*)Af, PART);
    k_stats256<<<48, blk, 0, stream>>>(PART, STATS);
    k_ln_apply<<<12288, blk, 0, stream>>>((const float4*)Af, STATS, (float4*)Bf, U3);
    // GLU pair GEMM (interleaved) -> U4 h bf16
    k_bgemm<1, 1><<<dim3(8, 4, 48), blk, 0, stream>>>(U3, SLAB, nullptr, 0, 256, 0, 256,
                                                      WGIB, 0, nullptr, nullptr, U4, SLAB, BIASI);
    // glu_out = h @ Wg3 -> XTf fp32
    k_bgemm<1, 0><<<dim3(8, 2, 48), blk, 0, stream>>>(U4, SLAB, nullptr, 0, 256, 0, 256,
                                                      WG3B, 0, bg3, XTf, nullptr, SLAB, nullptr);
    // (glu + xn)*(1+w) + bias + LN2 partials -> Af, PART
    k_finpre_ln<<<dim3(256, 48), blk, 0, stream>>>((const float4*)XTf, (const float4*)Bf,
                                                   (const float4*)WT, (const float4*)BT2,
                                                   (float4*)Af, PART);
    k_stats256<<<48, blk, 0, stream>>>(PART, STATS);
    k_out<<<dim3(1024, 4), blk, 0, stream>>>(Af, STATS, out);
}

// Round 6
// 511.389 us; speedup vs baseline: 4.5061x; 1.1134x over previous
//
#include <hip/hip_runtime.h>
#include <hip/hip_bf16.h>
#include <math.h>

#define DI __device__ __forceinline__
#define AS1 __attribute__((address_space(1)))
#define AS3 __attribute__((address_space(3)))

static constexpr int  B_ = 4, C_ = 256, N_ = 1024, L_ = 12, BL_ = 48;
static constexpr long SLAB = (long)N_ * C_;          // 262144 elems per (b,l)
static constexpr long TOT  = (long)BL_ * SLAB;       // 12,582,912 elems

typedef __attribute__((ext_vector_type(8))) short bf16x8;
typedef __attribute__((ext_vector_type(4))) float f32x4;

DI float b2f(uint hw) { return __builtin_bit_cast(float, (hw & 0xffffu) << 16); }
DI ushort f2b(float f) {
    uint u = __builtin_bit_cast(uint, f);
    u += 0x7FFFu + ((u >> 16) & 1u);
    return (ushort)(u >> 16);
}
DI uint pack2(float a, float b) {
    __hip_bfloat162 h = __float22bfloat162_rn(make_float2(a, b));
    uint r;
    __builtin_memcpy(&r, &h, 4);
    return r;
}

DI void gload16(const void* g, void* l) {
    __builtin_amdgcn_global_load_lds((AS1 uint*)g, (AS3 uint*)l, 16, 0, 0);
}

// ---------------- block reductions (256 threads, 4 waves) ----------------
DI float block_sum256(float v, float* sc) {
    #pragma unroll
    for (int o = 32; o > 0; o >>= 1) v += __shfl_xor(v, o, 64);
    int wid = threadIdx.x >> 6;
    __syncthreads();
    if ((threadIdx.x & 63) == 0) sc[wid] = v;
    __syncthreads();
    return sc[0] + sc[1] + sc[2] + sc[3];
}
DI float block_max256(float v, float* sc) {
    #pragma unroll
    for (int o = 32; o > 0; o >>= 1) v = fmaxf(v, __shfl_xor(v, o, 64));
    int wid = threadIdx.x >> 6;
    __syncthreads();
    if ((threadIdx.x & 63) == 0) sc[wid] = v;
    __syncthreads();
    return fmaxf(fmaxf(sc[0], sc[1]), fmaxf(sc[2], sc[3]));
}

// ---------------- adp = softmax(relu(nv1@nv2), axis=1), bf16 out ----------------
__global__ __launch_bounds__(256) void k_adp(const float* __restrict__ nv1,
                                             const float* __restrict__ nv2,
                                             ushort* __restrict__ adp) {
    __shared__ float r[6];
    __shared__ float sc[4];
    int row = blockIdx.x, tid = threadIdx.x;
    if (tid < 6) r[tid] = nv1[row * 6 + tid];
    __syncthreads();
    float e[4];
    #pragma unroll
    for (int q = 0; q < 4; q++) {
        int j = tid + q * 256;
        float s = 0.f;
        #pragma unroll
        for (int k = 0; k < 6; k++) s += r[k] * nv2[k * 1024 + j];
        e[q] = s > 0.f ? s : 0.f;
    }
    float m = fmaxf(fmaxf(e[0], e[1]), fmaxf(e[2], e[3]));
    m = block_max256(m, sc);
    float ps = 0.f;
    #pragma unroll
    for (int q = 0; q < 4; q++) { e[q] = __expf(e[q] - m); ps += e[q]; }
    ps = block_sum256(ps, sc);
    float rinv = 1.f / ps;
    #pragma unroll
    for (int q = 0; q < 4; q++) adp[(long)row * 1024 + tid + q * 256] = f2b(e[q] * rinv);
}

// ------- transpose in: x[b][c][n][l] -> Xb[(b*12+l)][n][c] bf16 + fp32 copy -------
__global__ __launch_bounds__(256) void k_tin(const float* __restrict__ x,
                                             ushort* __restrict__ xb,
                                             float* __restrict__ xf) {
    __shared__ float t[64][65];
    int nl0 = blockIdx.x * 64, c0 = blockIdx.y * 64, b = blockIdx.z;
    int lx = threadIdx.x & 63, ly = threadIdx.x >> 6;
    #pragma unroll
    for (int i = 0; i < 16; i++) {
        int c = c0 + ly + i * 4;
        t[ly + i * 4][lx] = x[(long)(b * 256 + c) * 12288 + nl0 + lx];
    }
    __syncthreads();
    #pragma unroll
    for (int i = 0; i < 16; i++) {
        int nl = nl0 + ly + i * 4;
        int n = nl / 12, l = nl % 12;
        long idx = ((long)(b * 12 + l) * 1024 + n) * 256 + c0 + lx;
        float v = t[lx][ly + i * 4];
        xb[idx] = f2b(v);
        xf[idx] = v;
    }
}

// ---------------- per-bl transpose Xb[n][c] -> XTT[c][n] (bf16) ----------------
__global__ __launch_bounds__(256) void k_xtt(const ushort* __restrict__ X,
                                             ushort* __restrict__ XT) {
    __shared__ ushort t[64][68];
    int bl = blockIdx.z;
    int n0 = blockIdx.x * 64, c0 = blockIdx.y * 64;
    int lx = threadIdx.x & 63, ly = threadIdx.x >> 6;
    const ushort* Xp = X + (long)bl * SLAB;
    #pragma unroll
    for (int i = 0; i < 16; i++)
        t[ly + i * 4][lx] = Xp[(long)(n0 + ly + i * 4) * 256 + c0 + lx];
    __syncthreads();
    ushort* Tp = XT + (long)bl * SLAB;
    #pragma unroll
    for (int i = 0; i < 16; i++)
        Tp[(long)(c0 + ly + i * 4) * 1024 + n0 + lx] = t[lx][ly + i * 4];
}

// -------- GAT weight transposes 256x256 fp32 [c][o] -> bf16 [o][c] --------
__global__ __launch_bounds__(256) void k_wt2(const float* __restrict__ S0, ushort* __restrict__ D0,
                                             const float* __restrict__ S1, ushort* __restrict__ D1) {
    __shared__ float t[64][65];
    const float* S = blockIdx.z ? S1 : S0;
    ushort* D = blockIdx.z ? D1 : D0;
    int c0 = blockIdx.x * 64, o0 = blockIdx.y * 64;
    int lx = threadIdx.x & 63, ly = threadIdx.x >> 6;
    #pragma unroll
    for (int i = 0; i < 16; i++)
        t[ly + i * 4][lx] = S[(long)(c0 + ly + i * 4) * 256 + o0 + lx];
    __syncthreads();
    #pragma unroll
    for (int i = 0; i < 16; i++)
        D[(long)(o0 + ly + i * 4) * 256 + c0 + lx] = f2b(t[lx][ly + i * 4]);
}

// ---------------- fp32 -> bf16 straight cast ----------------
__global__ __launch_bounds__(256) void k_wconv(const float* __restrict__ S, ushort* __restrict__ D) {
    long i = (long)blockIdx.x * 256 + threadIdx.x;
    D[i] = f2b(S[i]);
}

// ------- interleaved GLU weights: WGI[p*32+q] = (q<16 ? Wg1 : Wg2) row p*16+q%16 -------
__global__ __launch_bounds__(256) void k_wgi(const float* __restrict__ W1, const float* __restrict__ b1,
                                             const float* __restrict__ W2, const float* __restrict__ b2,
                                             ushort* __restrict__ WGI, float* __restrict__ BI) {
    int n = blockIdx.x, p = n >> 5, q = n & 31;
    const float* src = (q < 16) ? W1 + (long)(p * 16 + q) * 256
                                : W2 + (long)(p * 16 + q - 16) * 256;
    WGI[(long)n * 256 + threadIdx.x] = f2b(src[threadIdx.x]);
    if (threadIdx.x == 0) BI[n] = (q < 16) ? b1[p * 16 + q] : b2[p * 16 + q - 16];
}

// ----- va = W @ a pair -----
__global__ __launch_bounds__(256) void k_va(const float* __restrict__ W, const float* __restrict__ a,
                                            float* __restrict__ va) {
    __shared__ float sc[4];
    int c = blockIdx.x, t = threadIdx.x;
    float w = W[(long)c * 256 + t];
    float s1 = block_sum256(w * a[t], sc);
    float s2 = block_sum256(w * a[256 + t], sc);
    if (t == 0) { va[c] = s1; va[256 + c] = s2; }
}

// ------- weight/bias prep: wt[n][c] = w[c][n]+1, bt[n][c] = b[c][n] -------
__global__ __launch_bounds__(256) void k_wtprep(const float* __restrict__ w,
                                                const float* __restrict__ b,
                                                float* __restrict__ wt,
                                                float* __restrict__ bt) {
    int n = blockIdx.x, c = threadIdx.x;
    wt[(long)n * 256 + c] = w[(long)c * 1024 + n] + 1.f;
    bt[(long)n * 256 + c] = b[(long)c * 1024 + n];
}

// ------- pack mask bits -------
__global__ __launch_bounds__(256) void k_maskpack(const int* __restrict__ dg,
                                                  uint* __restrict__ maskw) {
    int w = blockIdx.x * 256 + threadIdx.x;
    int row = w >> 5, wo = w & 31;
    uint m = 0;
    #pragma unroll
    for (int b = 0; b < 32; b++)
        m |= (dg[(long)row * 1024 + wo * 32 + b] > 0 ? 1u : 0u) << b;
    maskw[w] = m;
}

// ------- bf16 MFMA GEMM: C[m][n] = sum_k A[m][k] * Bt[n][k] (+bias[n]) -------
template<int NPAIR, int GLU>
__global__ __launch_bounds__(256) void k_bgemm(
    const ushort* __restrict__ A0, long sA0,
    const ushort* __restrict__ A1, long sA1,
    int lda, int K0, int KK,
    const ushort* __restrict__ Bt, long sBt,
    const float* __restrict__ bias,
    float* __restrict__ Cf, ushort* __restrict__ Cb, long sC,
    const float* __restrict__ biasi) {
    __shared__ ushort As[128 * 32];
    __shared__ ushort Bs[128 * 32];
    const int tid = threadIdx.x;
    const int bl = blockIdx.z;
    const int m0 = blockIdx.x * 128, n0 = blockIdx.y * 128;
    const int N = gridDim.y * 128;
    const int lane = tid & 63, w = tid >> 6;
    const int wm = (w >> 1) * 64, wn = (w & 1) * 64;
    const int sr = tid >> 2, sk = (tid & 3) * 8;
    const int fr = lane & 15, fk = (lane >> 4) * 8;
    f32x4 acc[4][4] = {};
    const ushort* Ab0 = A0 + (long)bl * sA0;
    const ushort* Ab1 = (NPAIR == 2) ? A1 + (long)bl * sA1 : nullptr;
    const ushort* Bb = Bt + (long)bl * sBt;
    for (int k0 = 0; k0 < KK; k0 += 32) {
        const ushort* Asrc = Ab0; int kl = k0;
        if (NPAIR == 2 && k0 >= K0) { Asrc = Ab1; kl = k0 - K0; }
        __syncthreads();
        gload16(&Asrc[(long)(m0 + sr) * lda + kl + sk],      &As[sr * 32 + sk]);
        gload16(&Asrc[(long)(m0 + sr + 64) * lda + kl + sk], &As[(sr + 64) * 32 + sk]);
        gload16(&Bb[(long)(n0 + sr) * KK + k0 + sk],         &Bs[sr * 32 + sk]);
        gload16(&Bb[(long)(n0 + sr + 64) * KK + k0 + sk],    &Bs[(sr + 64) * 32 + sk]);
        __syncthreads();
        bf16x8 af[4], bg[4];
        #pragma unroll
        for (int i = 0; i < 4; i++) {
            af[i] = *(const bf16x8*)&As[(wm + i * 16 + fr) * 32 + fk];
            bg[i] = *(const bf16x8*)&Bs[(wn + i * 16 + fr) * 32 + fk];
        }
        #pragma unroll
        for (int i = 0; i < 4; i++)
            #pragma unroll
            for (int j = 0; j < 4; j++)
                acc[i][j] = __builtin_amdgcn_mfma_f32_16x16x32_bf16(af[i], bg[j], acc[i][j], 0, 0, 0);
    }
    const int cn = lane & 15, rb = (lane >> 4) * 4;
    if (GLU) {
        #pragma unroll
        for (int nt = 0; nt < 4; nt += 2) {
            int n1 = n0 + wn + nt * 16 + cn;          // interleaved col (g1 half)
            int hcol = ((n1 >> 5) << 4) + cn;         // original col p*16+cn
            float b1 = biasi[n1], b2 = biasi[n1 + 16];
            #pragma unroll
            for (int i = 0; i < 4; i++) {
                #pragma unroll
                for (int r = 0; r < 4; r++) {
                    int m = m0 + wm + i * 16 + rb + r;
                    float g1 = acc[i][nt][r] + b1;
                    float g2 = acc[i][nt + 1][r] + b2;
                    float h = g1 / (1.f + __expf(-g2));
                    Cb[(long)bl * sC + (long)m * 256 + hcol] = f2b(h);
                }
            }
        }
    } else {
        #pragma unroll
        for (int j = 0; j < 4; j++) {
            int n = n0 + wn + j * 16 + cn;
            float bv = bias ? bias[n] : 0.f;
            #pragma unroll
            for (int i = 0; i < 4; i++) {
                #pragma unroll
                for (int r = 0; r < 4; r++) {
                    int m = m0 + wm + i * 16 + rb + r;
                    float v = acc[i][j][r] + bv;
                    long idx = (long)bl * sC + (long)m * N + n;
                    if (Cf) Cf[idx] = v;
                    if (Cb) Cb[idx] = f2b(v);
                }
            }
        }
    }
}

// ---------------- w1/w2 GEMV ----------------
__global__ __launch_bounds__(256) void k_dots(const ushort* __restrict__ X,
                                              const float* __restrict__ va,
                                              float* __restrict__ o1,
                                              float* __restrict__ o2) {
    int wid = threadIdx.x >> 6, lane = threadIdx.x & 63;
    long row = (long)blockIdx.x * 4 + wid;
    uint2 xv = *(const uint2*)(X + row * 256 + lane * 4);
    float x0 = b2f(xv.x), x1 = b2f(xv.x >> 16), x2 = b2f(xv.y), x3 = b2f(xv.y >> 16);
    float4 v1 = *(const float4*)&va[lane * 4];
    float4 v2 = *(const float4*)&va[256 + lane * 4];
    float s1 = x0 * v1.x + x1 * v1.y + x2 * v1.z + x3 * v1.w;
    float s2 = x0 * v2.x + x1 * v2.y + x2 * v2.z + x3 * v2.w;
    #pragma unroll
    for (int o = 32; o > 0; o >>= 1) { s1 += __shfl_xor(s1, o, 64); s2 += __shfl_xor(s2, o, 64); }
    if (lane == 0) { o1[row] = s1; o2[row] = s2; }
}

// ------- per-bl global max of w2 (any m >= row max is exact after normalization) -------
__global__ __launch_bounds__(256) void k_w2max(const float* __restrict__ w2v,
                                               float* __restrict__ w2m) {
    __shared__ float sc[4];
    int bl = blockIdx.x;
    float4 v = *(const float4*)&w2v[(long)bl * 1024 + threadIdx.x * 4];
    float m = fmaxf(fmaxf(v.x, v.y), fmaxf(v.z, v.w));
    m = block_max256(m, sc);
    if (threadIdx.x == 0) w2m[bl] = m;
}

// ------- MFMA attention v3: no max-pass, no dbuf, conflict-free LDS, 64 rows/block ----
__global__ __launch_bounds__(256) void k_attn_mf(
    const ushort* __restrict__ WhT,   // [48][256][1024] bf16
    const float* __restrict__ w1v, const float* __restrict__ w2v,
    const float* __restrict__ w2m,    // [48]
    const uint* __restrict__ maskw,   // [1024][32]
    ushort* __restrict__ outB) {
    __shared__ ushort P2[32 * 64 * 8];   // [kq][row][8] 32 KB
    __shared__ float w2s[1024];
    __shared__ float w1s[64];
    __shared__ uint msk[64 * 33];        // padded stride 33
    __shared__ float psum[4][64];
    __shared__ float rsv[64];
    int d = blockIdx.x;                  // 768 blocks
    int lidx = (d & 7) * 96 + (d >> 3);  // XCD-chunked: 6 bl per XCD
    int bl = lidx >> 4;
    int i0 = (lidx & 15) * 64;
    int tid = threadIdx.x;
    #pragma unroll
    for (int q = 0; q < 4; q++) w2s[tid + q * 256] = w2v[(long)bl * 1024 + tid + q * 256];
    if (tid < 64) w1s[tid] = w1v[(long)bl * 1024 + i0 + tid];
    {   // mask load: 2048 words, coalesced, store at padded stride
        const uint4* gm = (const uint4*)(maskw + (long)i0 * 32);
        uint4 ma = gm[tid * 2], mb = gm[tid * 2 + 1];
        int r0 = tid >> 2, w0 = (tid & 3) * 8;
        uint* mp = &msk[r0 * 33 + w0];
        mp[0] = ma.x; mp[1] = ma.y; mp[2] = ma.z; mp[3] = ma.w;
        mp[4] = mb.x; mp[5] = mb.y; mp[6] = mb.z; mp[7] = mb.w;
    }
    __syncthreads();
    const int row = tid & 63, jt = tid >> 6;
    const float w1r = w1s[row];
    float e0 = w1r + w2m[bl];
    const float mr = (e0 > 0.f) ? e0 : 0.2f * e0;   // >= every masked score in row
    float sloc = 0.f;
    const int lane = tid & 63, w = tid >> 6;
    const int wn = w * 64;
    const int fr = lane & 15, fk8 = (lane >> 4) * 8;
    f32x4 acc[4][4] = {};
    const ushort* bp = WhT + (long)bl * SLAB;
    #pragma unroll 1
    for (int jc = 0; jc < 4; jc++) {
        int j0 = jc * 256;
        uint mw0 = msk[row * 33 + jc * 8 + jt * 2];
        uint mw1 = msk[row * 33 + jc * 8 + jt * 2 + 1];
        #pragma unroll
        for (int u = 0; u < 8; u++) {
            uint mg = ((u & 4) ? mw1 : mw0) >> ((u & 3) * 8);
            int jb = j0 + jt * 64 + u * 8;
            float p[8];
            #pragma unroll
            for (int t = 0; t < 8; t++) {
                float e = w1r + w2s[jb + t];
                e = (e > 0.f) ? e : 0.2f * e;
                float pp = __expf(e - mr);
                p[t] = ((mg >> t) & 1) ? pp : 0.f;
                sloc += p[t];
            }
            uint4 pv;
            pv.x = pack2(p[0], p[1]);
            pv.y = pack2(p[2], p[3]);
            pv.z = pack2(p[4], p[5]);
            pv.w = pack2(p[6], p[7]);
            *(uint4*)((char*)P2 + ((jt * 8 + u) * 64 + row) * 16) = pv;
        }
        __syncthreads();
        #pragma unroll
        for (int ks = 0; ks < 8; ks++) {
            int kb = ks * 32 + fk8;
            bf16x8 bg[4], af[4];
            #pragma unroll
            for (int nt = 0; nt < 4; nt++)
                bg[nt] = *(const bf16x8*)&bp[(long)(wn + nt * 16 + fr) * 1024 + j0 + kb];
            int kq = ks * 4 + (lane >> 4);
            #pragma unroll
            for (int mt = 0; mt < 4; mt++)
                af[mt] = *(const bf16x8*)((char*)P2 + (kq * 64 + mt * 16 + fr) * 16);
            #pragma unroll
            for (int mt = 0; mt < 4; mt++)
                #pragma unroll
                for (int nt = 0; nt < 4; nt++)
                    acc[mt][nt] = __builtin_amdgcn_mfma_f32_16x16x32_bf16(
                        af[mt], bg[nt], acc[mt][nt], 0, 0, 0);
        }
        __syncthreads();
    }
    psum[jt][row] = sloc;
    __syncthreads();
    if (tid < 64)
        rsv[tid] = 1.f / (psum[0][tid] + psum[1][tid] + psum[2][tid] + psum[3][tid]);
    __syncthreads();
    #pragma unroll
    for (int mt = 0; mt < 4; mt++) {
        #pragma unroll
        for (int r = 0; r < 4; r++) {
            int i = mt * 16 + (lane >> 4) * 4 + r;
            float sc = rsv[i];
            #pragma unroll
            for (int nt = 0; nt < 4; nt++) {
                int c = wn + nt * 16 + fr;
                float v = acc[mt][nt][r] * sc;
                v = (v > 0.f) ? v : __expf(v) - 1.f;       // elu
                outB[(long)bl * SLAB + (long)(i0 + i) * 256 + c] = f2b(v);
            }
        }
    }
}

// ------- fuse: a_s*gat(bf16) + (1-a_s)*gcn(f32) + x_in(f32), + LN partials -------
__global__ __launch_bounds__(256) void k_fuse_ln(const ushort* __restrict__ gat,
                                                 const float4* __restrict__ gcn,
                                                 const float4* __restrict__ xf,
                                                 const float* __restrict__ alpha,
                                                 float4* __restrict__ o,
                                                 float2* __restrict__ part) {
    __shared__ float sc[4];
    int bl = blockIdx.y;
    long i = (long)bl * 65536 + blockIdx.x * 256 + threadIdx.x;
    float as = 1.f / (1.f + __expf(-alpha[0]));
    float bs = 1.f - as;
    uint2 hv = ((const uint2*)gat)[i];
    float4 g = gcn[i], x = xf[i];
    float4 v = make_float4(as * b2f(hv.x) + bs * g.x + x.x,
                           as * b2f(hv.x >> 16) + bs * g.y + x.y,
                           as * b2f(hv.y) + bs * g.z + x.z,
                           as * b2f(hv.y >> 16) + bs * g.w + x.w);
    o[i] = v;
    float s = v.x + v.y + v.z + v.w;
    float q = v.x * v.x + v.y * v.y + v.z * v.z + v.w * v.w;
    s = block_sum256(s, sc);
    q = block_sum256(q, sc);
    if (threadIdx.x == 0) part[bl * 256 + blockIdx.x] = make_float2(s, q);
}

// ------- stats from 256 partials per slab -------
__global__ __launch_bounds__(256) void k_stats256(const float2* __restrict__ part,
                                                  float2* __restrict__ stats) {
    __shared__ float sc[4];
    int bl = blockIdx.x;
    float2 v = part[bl * 256 + threadIdx.x];
    float s = block_sum256(v.x, sc);
    float q = block_sum256(v.y, sc);
    if (threadIdx.x == 0) {
        float mean = s / (float)SLAB;
        float var = q / (float)SLAB - mean * mean;
        stats[bl] = make_float2(mean, 1.f / sqrtf(var + 1e-5f));
    }
}

__global__ __launch_bounds__(256) void k_ln_apply(const float4* __restrict__ x,
                                                  const float2* __restrict__ stats,
                                                  float4* __restrict__ o,
                                                  ushort* __restrict__ ob) {
    long i = (long)blockIdx.x * 256 + threadIdx.x;
    int bl = (int)(i >> 16);
    float2 st = stats[bl];
    float4 v = x[i];
    float o0 = (v.x - st.x) * st.y, o1 = (v.y - st.x) * st.y;
    float o2 = (v.z - st.x) * st.y, o3 = (v.w - st.x) * st.y;
    o[i] = make_float4(o0, o1, o2, o3);
    uint2 ow;
    ow.x = pack2(o0, o1);
    ow.y = pack2(o2, o3);
    ((uint2*)ob)[i] = ow;
}

// ------- final pre-LN: (glu + xn)*(1+w) + bias, + LN partials -------
__global__ __launch_bounds__(256) void k_finpre_ln(const float4* __restrict__ glu,
                                                   const float4* __restrict__ xn,
                                                   const float4* __restrict__ wt,
                                                   const float4* __restrict__ bt,
                                                   float4* __restrict__ o,
                                                   float2* __restrict__ part) {
    __shared__ float sc[4];
    int bl = blockIdx.y;
    long i = (long)bl * 65536 + blockIdx.x * 256 + threadIdx.x;
    long wi = i & 65535;
    float4 g = glu[i], x = xn[i], w = wt[wi], b = bt[wi];
    float4 v = make_float4((g.x + x.x) * w.x + b.x, (g.y + x.y) * w.y + b.y,
                           (g.z + x.z) * w.z + b.z, (g.w + x.w) * w.w + b.w);
    o[i] = v;
    float s = v.x + v.y + v.z + v.w;
    float q = v.x * v.x + v.y * v.y + v.z * v.z + v.w * v.w;
    s = block_sum256(s, sc);
    q = block_sum256(q, sc);
    if (threadIdx.x == 0) part[bl * 256 + blockIdx.x] = make_float2(s, q);
}

// ------- final normalize + transpose back to [b][c][n][l] -------
__global__ __launch_bounds__(256) void k_out(const float* __restrict__ x,
                                             const float2* __restrict__ stats,
                                             float* __restrict__ out) {
    int n = blockIdx.x, b = blockIdx.y, c = threadIdx.x;
    float v[12];
    #pragma unroll
    for (int l = 0; l < 12; l++) {
        float2 st = stats[b * 12 + l];
        float t = x[(long)(b * 12 + l) * SLAB + (long)n * 256 + c];
        v[l] = (t - st.x) * st.y;
    }
    float4* op = (float4*)(out + ((long)(b * 256 + c) * 1024 + n) * 12);
    op[0] = make_float4(v[0], v[1], v[2], v[3]);
    op[1] = make_float4(v[4], v[5], v[6], v[7]);
    op[2] = make_float4(v[8], v[9], v[10], v[11]);
}

// =================================================================
extern "C" void kernel_launch(void* const* d_in, const int* in_sizes, int n_in,
                              void* d_out, int out_size, void* d_ws, size_t ws_size,
                              hipStream_t stream) {
    (void)in_sizes; (void)n_in; (void)out_size; (void)ws_size;
    const float* x_in = (const float*)d_in[0];
    const int*   dg   = (const int*)d_in[1];
    const float* nv1  = (const float*)d_in[2];
    const float* nv2  = (const float*)d_in[3];
    const float* Wmlp = (const float*)d_in[4];
    const float* bmlp = (const float*)d_in[5];
    const float* Wg0  = (const float*)d_in[6];
    const float* ag0  = (const float*)d_in[7];
    const float* Wgo  = (const float*)d_in[8];
    const float* ago  = (const float*)d_in[9];
    const float* Wg1  = (const float*)d_in[10];
    const float* bg1  = (const float*)d_in[11];
    const float* Wg2  = (const float*)d_in[12];
    const float* bg2  = (const float*)d_in[13];
    const float* Wg3  = (const float*)d_in[14];
    const float* bg3  = (const float*)d_in[15];
    const float* alpha = (const float*)d_in[16];
    const float* wgt  = (const float*)d_in[17];
    const float* bia  = (const float*)d_in[18];
    float* out = (float*)d_out;

    // ---- workspace (~208 MB; Af aliases the dead U1+U2 region) ----
    float* XTf = (float*)d_ws;          // fp32 x_in copy; later glu3 out
    float* Bf  = XTf + TOT;             // fp32 gcn; later xn
    ushort* U1 = (ushort*)(Bf + TOT);   // Xb bf16
    ushort* U2 = U1 + TOT;              // XTT; later g (attn1 out)
    float* Af  = (float*)U1;            // fp32, live only after U1/U2 dead
    ushort* U3 = U2 + TOT;              // x1b; later gat bf16; later xn bf16
    ushort* U4 = U3 + TOT;              // WhT; later h bf16
    ushort* ADPB = U4 + TOT;            // [1024][1024]
    ushort* WMLPB = ADPB + (long)1024 * 1024;
    ushort* WG0T = WMLPB + 131072;
    ushort* WGOT = WG0T + 65536;
    ushort* WGIB = WGOT + 65536;        // [512][256] interleaved g1/g2
    ushort* WG3B = WGIB + 131072;
    float* BIASI = (float*)(WG3B + 65536);  // 512
    float* VA = BIASI + 512;                // 1024
    float* W1V = VA + 1024;
    float* W2V = W1V + 49152;
    float* W2M = W2V + 49152;               // 48 (+pad)
    uint* MASKW = (uint*)(W2M + 64);        // 32768
    float2* PART = (float2*)(MASKW + 32768); // [48][256]
    float2* STATS = PART + 48 * 256;
    float* WT = (float*)(STATS + 48);
    float* BT2 = WT + SLAB;

    dim3 blk(256);
    // prep
    k_wt2<<<dim3(4, 4, 2), blk, 0, stream>>>(Wg0, WG0T, Wgo, WGOT);
    k_wconv<<<512, blk, 0, stream>>>(Wmlp, WMLPB);
    k_wconv<<<256, blk, 0, stream>>>(Wg3, WG3B);
    k_wgi<<<512, blk, 0, stream>>>(Wg1, bg1, Wg2, bg2, WGIB, BIASI);
    k_va<<<256, blk, 0, stream>>>(Wg0, ag0, VA);
    k_va<<<256, blk, 0, stream>>>(Wgo, ago, VA + 512);
    k_wtprep<<<1024, blk, 0, stream>>>(wgt, bia, WT, BT2);
    k_adp<<<1024, blk, 0, stream>>>(nv1, nv2, ADPB);
    k_maskpack<<<128, blk, 0, stream>>>(dg, MASKW);
    k_tin<<<dim3(192, 4, 4), blk, 0, stream>>>(x_in, U1, XTf);
    k_xtt<<<dim3(16, 4, 48), blk, 0, stream>>>(U1, U2);
    // x1 = adp @ x  (Bt = XTT) -> U3 bf16
    k_bgemm<1, 0><<<dim3(8, 2, 48), blk, 0, stream>>>(ADPB, 0, nullptr, 0, 1024, 0, 1024,
                                                      U2, SLAB, nullptr, nullptr, U3, SLAB, nullptr);
    // gcn = [x|x1] @ Wmlp(o,c) + b -> Bf fp32
    k_bgemm<2, 0><<<dim3(8, 2, 48), blk, 0, stream>>>(U1, SLAB, U3, SLAB, 256, 256, 512,
                                                      WMLPB, 0, bmlp, Bf, nullptr, SLAB, nullptr);
    // GAT layer 1
    k_dots<<<12288, blk, 0, stream>>>(U1, VA, W1V, W2V);
    k_w2max<<<48, blk, 0, stream>>>(W2V, W2M);
    k_bgemm<1, 0><<<dim3(2, 8, 48), blk, 0, stream>>>(WG0T, 0, nullptr, 0, 256, 0, 256,
                                                      U1, SLAB, nullptr, nullptr, U4, SLAB, nullptr);
    k_attn_mf<<<768, blk, 0, stream>>>(U4, W1V, W2V, W2M, MASKW, U2);
    // GAT layer 2
    k_dots<<<12288, blk, 0, stream>>>(U2, VA + 512, W1V, W2V);
    k_w2max<<<48, blk, 0, stream>>>(W2V, W2M);
    k_bgemm<1, 0><<<dim3(2, 8, 48), blk, 0, stream>>>(WGOT, 0, nullptr, 0, 256, 0, 256,
                                                      U2, SLAB, nullptr, nullptr, U4, SLAB, nullptr);
    k_attn_mf<<<768, blk, 0, stream>>>(U4, W1V, W2V, W2M, MASKW, U3);
    // fuse + LN1 partials -> Af, PART
    k_fuse_ln<<<dim3(256, 48), blk, 0, stream>>>(U3, (const float4*)Bf, (const float4*)XTf,
                                                 alpha, (float4*)Af, PART);
    k_stats256<<<48, blk, 0, stream>>>(PART, STATS);
    k_ln_apply<<<12288, blk, 0, stream>>>((const float4*)Af, STATS, (float4*)Bf, U3);
    // GLU pair GEMM (interleaved) -> U4 h bf16
    k_bgemm<1, 1><<<dim3(8, 4, 48), blk, 0, stream>>>(U3, SLAB, nullptr, 0, 256, 0, 256,
                                                      WGIB, 0, nullptr, nullptr, U4, SLAB, BIASI);
    // glu_out = h @ Wg3 -> XTf fp32
    k_bgemm<1, 0><<<dim3(8, 2, 48), blk, 0, stream>>>(U4, SLAB, nullptr, 0, 256, 0, 256,
                                                      WG3B, 0, bg3, XTf, nullptr, SLAB, nullptr);
    // (glu + xn)*(1+w) + bias + LN2 partials -> Af, PART
    k_finpre_ln<<<dim3(256, 48), blk, 0, stream>>>((const float4*)XTf, (const float4*)Bf,
                                                   (const float4*)WT, (const float4*)BT2,
                                                   (float4*)Af, PART);
    k_stats256<<<48, blk, 0, stream>>>(PART, STATS);
    k_out<<<dim3(1024, 4), blk, 0, stream>>>(Af, STATS, out);
}

// Round 7
// 502.250 us; speedup vs baseline: 4.5881x; 1.0182x over previous
//
#include <hip/hip_runtime.h>
#include <hip/hip_bf16.h>
#include <math.h>

#define DI __device__ __forceinline__
#define AS1 __attribute__((address_space(1)))
#define AS3 __attribute__((address_space(3)))

static constexpr int  B_ = 4, C_ = 256, N_ = 1024, L_ = 12, BL_ = 48;
static constexpr long SLAB = (long)N_ * C_;          // 262144 elems per (b,l)
static constexpr long TOT  = (long)BL_ * SLAB;       // 12,582,912 elems

typedef __attribute__((ext_vector_type(8))) short bf16x8;
typedef __attribute__((ext_vector_type(4))) float f32x4;

DI float b2f(uint hw) { return __builtin_bit_cast(float, (hw & 0xffffu) << 16); }
DI ushort f2b(float f) {
    uint u = __builtin_bit_cast(uint, f);
    u += 0x7FFFu + ((u >> 16) & 1u);
    return (ushort)(u >> 16);
}
DI uint pack2(float a, float b) {
    __hip_bfloat162 h = __float22bfloat162_rn(make_float2(a, b));
    uint r;
    __builtin_memcpy(&r, &h, 4);
    return r;
}

DI void gload16(const void* g, void* l) {
    __builtin_amdgcn_global_load_lds((AS1 uint*)g, (AS3 uint*)l, 16, 0, 0);
}

// ---------------- block reductions (256 threads, 4 waves) ----------------
DI float block_sum256(float v, float* sc) {
    #pragma unroll
    for (int o = 32; o > 0; o >>= 1) v += __shfl_xor(v, o, 64);
    int wid = threadIdx.x >> 6;
    __syncthreads();
    if ((threadIdx.x & 63) == 0) sc[wid] = v;
    __syncthreads();
    return sc[0] + sc[1] + sc[2] + sc[3];
}
DI float block_max256(float v, float* sc) {
    #pragma unroll
    for (int o = 32; o > 0; o >>= 1) v = fmaxf(v, __shfl_xor(v, o, 64));
    int wid = threadIdx.x >> 6;
    __syncthreads();
    if ((threadIdx.x & 63) == 0) sc[wid] = v;
    __syncthreads();
    return fmaxf(fmaxf(sc[0], sc[1]), fmaxf(sc[2], sc[3]));
}

// ---------------- adp = softmax(relu(nv1@nv2), axis=1), bf16 out ----------------
__global__ __launch_bounds__(256) void k_adp(const float* __restrict__ nv1,
                                             const float* __restrict__ nv2,
                                             ushort* __restrict__ adp) {
    __shared__ float r[6];
    __shared__ float sc[4];
    int row = blockIdx.x, tid = threadIdx.x;
    if (tid < 6) r[tid] = nv1[row * 6 + tid];
    __syncthreads();
    float e[4];
    #pragma unroll
    for (int q = 0; q < 4; q++) {
        int j = tid + q * 256;
        float s = 0.f;
        #pragma unroll
        for (int k = 0; k < 6; k++) s += r[k] * nv2[k * 1024 + j];
        e[q] = s > 0.f ? s : 0.f;
    }
    float m = fmaxf(fmaxf(e[0], e[1]), fmaxf(e[2], e[3]));
    m = block_max256(m, sc);
    float ps = 0.f;
    #pragma unroll
    for (int q = 0; q < 4; q++) { e[q] = __expf(e[q] - m); ps += e[q]; }
    ps = block_sum256(ps, sc);
    float rinv = 1.f / ps;
    #pragma unroll
    for (int q = 0; q < 4; q++) adp[(long)row * 1024 + tid + q * 256] = f2b(e[q] * rinv);
}

// ------- transpose in: x[b][c][n][l] -> Xb[(b*12+l)][n][c] bf16 + fp32 copy -------
__global__ __launch_bounds__(256) void k_tin(const float* __restrict__ x,
                                             ushort* __restrict__ xb,
                                             float* __restrict__ xf) {
    __shared__ float t[64][65];
    int nl0 = blockIdx.x * 64, c0 = blockIdx.y * 64, b = blockIdx.z;
    int lx = threadIdx.x & 63, ly = threadIdx.x >> 6;
    #pragma unroll
    for (int i = 0; i < 16; i++) {
        int c = c0 + ly + i * 4;
        t[ly + i * 4][lx] = x[(long)(b * 256 + c) * 12288 + nl0 + lx];
    }
    __syncthreads();
    #pragma unroll
    for (int i = 0; i < 16; i++) {
        int nl = nl0 + ly + i * 4;
        int n = nl / 12, l = nl % 12;
        long idx = ((long)(b * 12 + l) * 1024 + n) * 256 + c0 + lx;
        float v = t[lx][ly + i * 4];
        xb[idx] = f2b(v);
        xf[idx] = v;
    }
}

// ---------------- per-bl transpose Xb[n][c] -> XTT[c][n] (bf16) ----------------
__global__ __launch_bounds__(256) void k_xtt(const ushort* __restrict__ X,
                                             ushort* __restrict__ XT) {
    __shared__ ushort t[64][68];
    int bl = blockIdx.z;
    int n0 = blockIdx.x * 64, c0 = blockIdx.y * 64;
    int lx = threadIdx.x & 63, ly = threadIdx.x >> 6;
    const ushort* Xp = X + (long)bl * SLAB;
    #pragma unroll
    for (int i = 0; i < 16; i++)
        t[ly + i * 4][lx] = Xp[(long)(n0 + ly + i * 4) * 256 + c0 + lx];
    __syncthreads();
    ushort* Tp = XT + (long)bl * SLAB;
    #pragma unroll
    for (int i = 0; i < 16; i++)
        Tp[(long)(c0 + ly + i * 4) * 1024 + n0 + lx] = t[lx][ly + i * 4];
}

// -------- GAT weight transposes 256x256 fp32 [c][o] -> bf16 [o][c] --------
__global__ __launch_bounds__(256) void k_wt2(const float* __restrict__ S0, ushort* __restrict__ D0,
                                             const float* __restrict__ S1, ushort* __restrict__ D1) {
    __shared__ float t[64][65];
    const float* S = blockIdx.z ? S1 : S0;
    ushort* D = blockIdx.z ? D1 : D0;
    int c0 = blockIdx.x * 64, o0 = blockIdx.y * 64;
    int lx = threadIdx.x & 63, ly = threadIdx.x >> 6;
    #pragma unroll
    for (int i = 0; i < 16; i++)
        t[ly + i * 4][lx] = S[(long)(c0 + ly + i * 4) * 256 + o0 + lx];
    __syncthreads();
    #pragma unroll
    for (int i = 0; i < 16; i++)
        D[(long)(o0 + ly + i * 4) * 256 + c0 + lx] = f2b(t[lx][ly + i * 4]);
}

// ---------------- fp32 -> bf16 straight cast ----------------
__global__ __launch_bounds__(256) void k_wconv(const float* __restrict__ S, ushort* __restrict__ D) {
    long i = (long)blockIdx.x * 256 + threadIdx.x;
    D[i] = f2b(S[i]);
}

// ------- interleaved GLU weights: WGI[p*32+q] = (q<16 ? Wg1 : Wg2) row p*16+q%16 -------
__global__ __launch_bounds__(256) void k_wgi(const float* __restrict__ W1, const float* __restrict__ b1,
                                             const float* __restrict__ W2, const float* __restrict__ b2,
                                             ushort* __restrict__ WGI, float* __restrict__ BI) {
    int n = blockIdx.x, p = n >> 5, q = n & 31;
    const float* src = (q < 16) ? W1 + (long)(p * 16 + q) * 256
                                : W2 + (long)(p * 16 + q - 16) * 256;
    WGI[(long)n * 256 + threadIdx.x] = f2b(src[threadIdx.x]);
    if (threadIdx.x == 0) BI[n] = (q < 16) ? b1[p * 16 + q] : b2[p * 16 + q - 16];
}

// ----- va = W @ a pair -----
__global__ __launch_bounds__(256) void k_va(const float* __restrict__ W, const float* __restrict__ a,
                                            float* __restrict__ va) {
    __shared__ float sc[4];
    int c = blockIdx.x, t = threadIdx.x;
    float w = W[(long)c * 256 + t];
    float s1 = block_sum256(w * a[t], sc);
    float s2 = block_sum256(w * a[256 + t], sc);
    if (t == 0) { va[c] = s1; va[256 + c] = s2; }
}

// ------- weight/bias prep: wt[n][c] = w[c][n]+1, bt[n][c] = b[c][n] -------
__global__ __launch_bounds__(256) void k_wtprep(const float* __restrict__ w,
                                                const float* __restrict__ b,
                                                float* __restrict__ wt,
                                                float* __restrict__ bt) {
    int n = blockIdx.x, c = threadIdx.x;
    wt[(long)n * 256 + c] = w[(long)c * 1024 + n] + 1.f;
    bt[(long)n * 256 + c] = b[(long)c * 1024 + n];
}

// ------- pack mask bits -------
__global__ __launch_bounds__(256) void k_maskpack(const int* __restrict__ dg,
                                                  uint* __restrict__ maskw) {
    int w = blockIdx.x * 256 + threadIdx.x;
    int row = w >> 5, wo = w & 31;
    uint m = 0;
    #pragma unroll
    for (int b = 0; b < 32; b++)
        m |= (dg[(long)row * 1024 + wo * 32 + b] > 0 ? 1u : 0u) << b;
    maskw[w] = m;
}

// ------- bf16 MFMA GEMM, 2-phase pipelined: C[m][n] = sum_k A[m][k]*Bt[n][k] (+bias) ----
template<int NPAIR, int GLU>
__global__ __launch_bounds__(256) void k_bgemm(
    const ushort* __restrict__ A0, long sA0,
    const ushort* __restrict__ A1, long sA1,
    int lda, int K0, int KK,
    const ushort* __restrict__ Bt, long sBt,
    const float* __restrict__ bias,
    float* __restrict__ Cf, ushort* __restrict__ Cb, long sC,
    const float* __restrict__ biasi) {
    __shared__ ushort As[2][128 * 32];
    __shared__ ushort Bs[2][128 * 32];
    const int tid = threadIdx.x;
    const int bl = blockIdx.z;
    const int m0 = blockIdx.x * 128, n0 = blockIdx.y * 128;
    const int N = gridDim.y * 128;
    const int lane = tid & 63, w = tid >> 6;
    const int wm = (w >> 1) * 64, wn = (w & 1) * 64;
    const int sr = tid >> 2, sk = (tid & 3) * 8;
    const int fr = lane & 15, fk = (lane >> 4) * 8;
    f32x4 acc[4][4] = {};
    const ushort* Ab0 = A0 + (long)bl * sA0;
    const ushort* Ab1 = (NPAIR == 2) ? A1 + (long)bl * sA1 : nullptr;
    const ushort* Bb = Bt + (long)bl * sBt;

    auto stage = [&](int buf, int k0) {
        const ushort* Asrc = Ab0; int kl = k0;
        if (NPAIR == 2 && k0 >= K0) { Asrc = Ab1; kl = k0 - K0; }
        gload16(&Asrc[(long)(m0 + sr) * lda + kl + sk],      &As[buf][sr * 32 + sk]);
        gload16(&Asrc[(long)(m0 + sr + 64) * lda + kl + sk], &As[buf][(sr + 64) * 32 + sk]);
        gload16(&Bb[(long)(n0 + sr) * KK + k0 + sk],         &Bs[buf][sr * 32 + sk]);
        gload16(&Bb[(long)(n0 + sr + 64) * KK + k0 + sk],    &Bs[buf][(sr + 64) * 32 + sk]);
    };
    auto compute = [&](int buf) {
        bf16x8 af[4], bg[4];
        #pragma unroll
        for (int i = 0; i < 4; i++) {
            af[i] = *(const bf16x8*)&As[buf][(wm + i * 16 + fr) * 32 + fk];
            bg[i] = *(const bf16x8*)&Bs[buf][(wn + i * 16 + fr) * 32 + fk];
        }
        #pragma unroll
        for (int i = 0; i < 4; i++)
            #pragma unroll
            for (int j = 0; j < 4; j++)
                acc[i][j] = __builtin_amdgcn_mfma_f32_16x16x32_bf16(af[i], bg[j], acc[i][j], 0, 0, 0);
    };

    stage(0, 0);
    __syncthreads();                       // drains vmcnt(0)
    int cur = 0;
    for (int k0 = 32; k0 < KK; k0 += 32) {
        stage(cur ^ 1, k0);                // issue next tile, in flight under compute
        compute(cur);
        __syncthreads();                   // next tile landed + all waves done reading cur
        cur ^= 1;
    }
    compute(cur);

    const int cn = lane & 15, rb = (lane >> 4) * 4;
    if (GLU) {
        #pragma unroll
        for (int nt = 0; nt < 4; nt += 2) {
            int n1 = n0 + wn + nt * 16 + cn;          // interleaved col (g1 half)
            int hcol = ((n1 >> 5) << 4) + cn;         // original col p*16+cn
            float b1 = biasi[n1], b2 = biasi[n1 + 16];
            #pragma unroll
            for (int i = 0; i < 4; i++) {
                #pragma unroll
                for (int r = 0; r < 4; r++) {
                    int m = m0 + wm + i * 16 + rb + r;
                    float g1 = acc[i][nt][r] + b1;
                    float g2 = acc[i][nt + 1][r] + b2;
                    float h = g1 / (1.f + __expf(-g2));
                    Cb[(long)bl * sC + (long)m * 256 + hcol] = f2b(h);
                }
            }
        }
    } else {
        #pragma unroll
        for (int j = 0; j < 4; j++) {
            int n = n0 + wn + j * 16 + cn;
            float bv = bias ? bias[n] : 0.f;
            #pragma unroll
            for (int i = 0; i < 4; i++) {
                #pragma unroll
                for (int r = 0; r < 4; r++) {
                    int m = m0 + wm + i * 16 + rb + r;
                    float v = acc[i][j][r] + bv;
                    long idx = (long)bl * sC + (long)m * N + n;
                    if (Cf) Cf[idx] = v;
                    if (Cb) Cb[idx] = f2b(v);
                }
            }
        }
    }
}

// ---------------- w1/w2 GEMV ----------------
__global__ __launch_bounds__(256) void k_dots(const ushort* __restrict__ X,
                                              const float* __restrict__ va,
                                              float* __restrict__ o1,
                                              float* __restrict__ o2) {
    int wid = threadIdx.x >> 6, lane = threadIdx.x & 63;
    long row = (long)blockIdx.x * 4 + wid;
    uint2 xv = *(const uint2*)(X + row * 256 + lane * 4);
    float x0 = b2f(xv.x), x1 = b2f(xv.x >> 16), x2 = b2f(xv.y), x3 = b2f(xv.y >> 16);
    float4 v1 = *(const float4*)&va[lane * 4];
    float4 v2 = *(const float4*)&va[256 + lane * 4];
    float s1 = x0 * v1.x + x1 * v1.y + x2 * v1.z + x3 * v1.w;
    float s2 = x0 * v2.x + x1 * v2.y + x2 * v2.z + x3 * v2.w;
    #pragma unroll
    for (int o = 32; o > 0; o >>= 1) { s1 += __shfl_xor(s1, o, 64); s2 += __shfl_xor(s2, o, 64); }
    if (lane == 0) { o1[row] = s1; o2[row] = s2; }
}

// ------- per-bl global max of w2 (any m >= row max is exact after normalization) -------
__global__ __launch_bounds__(256) void k_w2max(const float* __restrict__ w2v,
                                               float* __restrict__ w2m) {
    __shared__ float sc[4];
    int bl = blockIdx.x;
    float4 v = *(const float4*)&w2v[(long)bl * 1024 + threadIdx.x * 4];
    float m = fmaxf(fmaxf(v.x, v.y), fmaxf(v.z, v.w));
    m = block_max256(m, sc);
    if (threadIdx.x == 0) w2m[bl] = m;
}

// ------- MFMA attention v4: 128-j chunks (16KB P), 64 rows/block, 4 blocks/CU -------
__global__ __launch_bounds__(256, 4) void k_attn_mf(
    const ushort* __restrict__ WhT,   // [48][256][1024] bf16
    const float* __restrict__ w1v, const float* __restrict__ w2v,
    const float* __restrict__ w2m,    // [48]
    const uint* __restrict__ maskw,   // [1024][32]
    ushort* __restrict__ outB) {
    __shared__ ushort P2[16 * 64 * 8];   // [kq][row][8] 16 KB
    __shared__ float w2s[1024];
    __shared__ float w1s[64];
    __shared__ uint msk[64 * 33];        // padded stride 33
    __shared__ float psum[4][64];
    __shared__ float rsv[64];
    int d = blockIdx.x;                  // 768 blocks
    int lidx = (d & 7) * 96 + (d >> 3);  // XCD-chunked: 6 bl per XCD
    int bl = lidx >> 4;
    int i0 = (lidx & 15) * 64;
    int tid = threadIdx.x;
    #pragma unroll
    for (int q = 0; q < 4; q++) w2s[tid + q * 256] = w2v[(long)bl * 1024 + tid + q * 256];
    if (tid < 64) w1s[tid] = w1v[(long)bl * 1024 + i0 + tid];
    {   // mask load: 2048 words, coalesced, store at padded stride
        const uint4* gm = (const uint4*)(maskw + (long)i0 * 32);
        uint4 ma = gm[tid * 2], mb = gm[tid * 2 + 1];
        int r0 = tid >> 2, w0 = (tid & 3) * 8;
        uint* mp = &msk[r0 * 33 + w0];
        mp[0] = ma.x; mp[1] = ma.y; mp[2] = ma.z; mp[3] = ma.w;
        mp[4] = mb.x; mp[5] = mb.y; mp[6] = mb.z; mp[7] = mb.w;
    }
    __syncthreads();
    const int row = tid & 63, jt = tid >> 6;
    const float w1r = w1s[row];
    float e0 = w1r + w2m[bl];
    const float mr = (e0 > 0.f) ? e0 : 0.2f * e0;   // >= every masked score in row
    float sloc = 0.f;
    const int lane = tid & 63, w = tid >> 6;
    const int wn = w * 64;
    const int fr = lane & 15, fk8 = (lane >> 4) * 8;
    f32x4 acc[4][4] = {};
    const ushort* bp = WhT + (long)bl * SLAB;
    #pragma unroll 1
    for (int jc = 0; jc < 8; jc++) {
        int j0 = jc * 128;
        uint mw = msk[row * 33 + jc * 4 + jt];       // thread's 32-j strip this chunk
        #pragma unroll
        for (int u = 0; u < 4; u++) {
            uint mg = mw >> (u * 8);
            int jb = j0 + jt * 32 + u * 8;
            float p[8];
            #pragma unroll
            for (int t = 0; t < 8; t++) {
                float e = w1r + w2s[jb + t];
                e = (e > 0.f) ? e : 0.2f * e;
                float pp = __expf(e - mr);
                p[t] = ((mg >> t) & 1) ? pp : 0.f;
                sloc += p[t];
            }
            uint4 pv;
            pv.x = pack2(p[0], p[1]);
            pv.y = pack2(p[2], p[3]);
            pv.z = pack2(p[4], p[5]);
            pv.w = pack2(p[6], p[7]);
            *(uint4*)((char*)P2 + ((jt * 4 + u) * 64 + row) * 16) = pv;
        }
        __syncthreads();
        #pragma unroll
        for (int ks = 0; ks < 4; ks++) {
            int kb = ks * 32 + fk8;
            bf16x8 bg[4], af[4];
            #pragma unroll
            for (int nt = 0; nt < 4; nt++)
                bg[nt] = *(const bf16x8*)&bp[(long)(wn + nt * 16 + fr) * 1024 + j0 + kb];
            int kq = ks * 4 + (lane >> 4);
            #pragma unroll
            for (int mt = 0; mt < 4; mt++)
                af[mt] = *(const bf16x8*)((char*)P2 + (kq * 64 + mt * 16 + fr) * 16);
            #pragma unroll
            for (int mt = 0; mt < 4; mt++)
                #pragma unroll
                for (int nt = 0; nt < 4; nt++)
                    acc[mt][nt] = __builtin_amdgcn_mfma_f32_16x16x32_bf16(
                        af[mt], bg[nt], acc[mt][nt], 0, 0, 0);
        }
        __syncthreads();
    }
    psum[jt][row] = sloc;
    __syncthreads();
    if (tid < 64)
        rsv[tid] = 1.f / (psum[0][tid] + psum[1][tid] + psum[2][tid] + psum[3][tid]);
    __syncthreads();
    #pragma unroll
    for (int mt = 0; mt < 4; mt++) {
        #pragma unroll
        for (int r = 0; r < 4; r++) {
            int i = mt * 16 + (lane >> 4) * 4 + r;
            float sc = rsv[i];
            #pragma unroll
            for (int nt = 0; nt < 4; nt++) {
                int c = wn + nt * 16 + fr;
                float v = acc[mt][nt][r] * sc;
                v = (v > 0.f) ? v : __expf(v) - 1.f;       // elu
                outB[(long)bl * SLAB + (long)(i0 + i) * 256 + c] = f2b(v);
            }
        }
    }
}

// ------- fuse: a_s*gat(bf16) + (1-a_s)*gcn(f32) + x_in(f32), + LN partials -------
__global__ __launch_bounds__(256) void k_fuse_ln(const ushort* __restrict__ gat,
                                                 const float4* __restrict__ gcn,
                                                 const float4* __restrict__ xf,
                                                 const float* __restrict__ alpha,
                                                 float4* __restrict__ o,
                                                 float2* __restrict__ part) {
    __shared__ float sc[4];
    int bl = blockIdx.y;
    long i = (long)bl * 65536 + blockIdx.x * 256 + threadIdx.x;
    float as = 1.f / (1.f + __expf(-alpha[0]));
    float bs = 1.f - as;
    uint2 hv = ((const uint2*)gat)[i];
    float4 g = gcn[i], x = xf[i];
    float4 v = make_float4(as * b2f(hv.x) + bs * g.x + x.x,
                           as * b2f(hv.x >> 16) + bs * g.y + x.y,
                           as * b2f(hv.y) + bs * g.z + x.z,
                           as * b2f(hv.y >> 16) + bs * g.w + x.w);
    o[i] = v;
    float s = v.x + v.y + v.z + v.w;
    float q = v.x * v.x + v.y * v.y + v.z * v.z + v.w * v.w;
    s = block_sum256(s, sc);
    q = block_sum256(q, sc);
    if (threadIdx.x == 0) part[bl * 256 + blockIdx.x] = make_float2(s, q);
}

// ------- stats from 256 partials per slab -------
__global__ __launch_bounds__(256) void k_stats256(const float2* __restrict__ part,
                                                  float2* __restrict__ stats) {
    __shared__ float sc[4];
    int bl = blockIdx.x;
    float2 v = part[bl * 256 + threadIdx.x];
    float s = block_sum256(v.x, sc);
    float q = block_sum256(v.y, sc);
    if (threadIdx.x == 0) {
        float mean = s / (float)SLAB;
        float var = q / (float)SLAB - mean * mean;
        stats[bl] = make_float2(mean, 1.f / sqrtf(var + 1e-5f));
    }
}

// ------- LN apply, bf16 out only -------
__global__ __launch_bounds__(256) void k_ln_apply(const float4* __restrict__ x,
                                                  const float2* __restrict__ stats,
                                                  ushort* __restrict__ ob) {
    long i = (long)blockIdx.x * 256 + threadIdx.x;
    int bl = (int)(i >> 16);
    float2 st = stats[bl];
    float4 v = x[i];
    uint2 ow;
    ow.x = pack2((v.x - st.x) * st.y, (v.y - st.x) * st.y);
    ow.y = pack2((v.z - st.x) * st.y, (v.w - st.x) * st.y);
    ((uint2*)ob)[i] = ow;
}

// ------- final pre-LN: (glu + LN1(afull))*(1+w) + bias, + LN2 partials -------
__global__ __launch_bounds__(256) void k_finpre_ln(const float4* __restrict__ glu,
                                                   const float4* __restrict__ afull,
                                                   const float2* __restrict__ stats1,
                                                   const float4* __restrict__ wt,
                                                   const float4* __restrict__ bt,
                                                   float4* __restrict__ o,
                                                   float2* __restrict__ part) {
    __shared__ float sc[4];
    int bl = blockIdx.y;
    long i = (long)bl * 65536 + blockIdx.x * 256 + threadIdx.x;
    long wi = i & 65535;
    float2 st = stats1[bl];
    float4 g = glu[i], a = afull[i], w = wt[wi], b = bt[wi];
    float4 v = make_float4((g.x + (a.x - st.x) * st.y) * w.x + b.x,
                           (g.y + (a.y - st.x) * st.y) * w.y + b.y,
                           (g.z + (a.z - st.x) * st.y) * w.z + b.z,
                           (g.w + (a.w - st.x) * st.y) * w.w + b.w);
    o[i] = v;
    float s = v.x + v.y + v.z + v.w;
    float q = v.x * v.x + v.y * v.y + v.z * v.z + v.w * v.w;
    s = block_sum256(s, sc);
    q = block_sum256(q, sc);
    if (threadIdx.x == 0) part[bl * 256 + blockIdx.x] = make_float2(s, q);
}

// ------- final normalize + transpose back to [b][c][n][l] -------
__global__ __launch_bounds__(256) void k_out(const float* __restrict__ x,
                                             const float2* __restrict__ stats,
                                             float* __restrict__ out) {
    int n = blockIdx.x, b = blockIdx.y, c = threadIdx.x;
    float v[12];
    #pragma unroll
    for (int l = 0; l < 12; l++) {
        float2 st = stats[b * 12 + l];
        float t = x[(long)(b * 12 + l) * SLAB + (long)n * 256 + c];
        v[l] = (t - st.x) * st.y;
    }
    float4* op = (float4*)(out + ((long)(b * 256 + c) * 1024 + n) * 12);
    op[0] = make_float4(v[0], v[1], v[2], v[3]);
    op[1] = make_float4(v[4], v[5], v[6], v[7]);
    op[2] = make_float4(v[8], v[9], v[10], v[11]);
}

// =================================================================
extern "C" void kernel_launch(void* const* d_in, const int* in_sizes, int n_in,
                              void* d_out, int out_size, void* d_ws, size_t ws_size,
                              hipStream_t stream) {
    (void)in_sizes; (void)n_in; (void)out_size; (void)ws_size;
    const float* x_in = (const float*)d_in[0];
    const int*   dg   = (const int*)d_in[1];
    const float* nv1  = (const float*)d_in[2];
    const float* nv2  = (const float*)d_in[3];
    const float* Wmlp = (const float*)d_in[4];
    const float* bmlp = (const float*)d_in[5];
    const float* Wg0  = (const float*)d_in[6];
    const float* ag0  = (const float*)d_in[7];
    const float* Wgo  = (const float*)d_in[8];
    const float* ago  = (const float*)d_in[9];
    const float* Wg1  = (const float*)d_in[10];
    const float* bg1  = (const float*)d_in[11];
    const float* Wg2  = (const float*)d_in[12];
    const float* bg2  = (const float*)d_in[13];
    const float* Wg3  = (const float*)d_in[14];
    const float* bg3  = (const float*)d_in[15];
    const float* alpha = (const float*)d_in[16];
    const float* wgt  = (const float*)d_in[17];
    const float* bia  = (const float*)d_in[18];
    float* out = (float*)d_out;

    // ---- workspace (~208 MB; Af aliases the dead U1+U2 region) ----
    float* XTf = (float*)d_ws;          // fp32 x_in copy; later glu3 out
    float* Bf  = XTf + TOT;             // fp32 gcn; later final pre-LN
    ushort* U1 = (ushort*)(Bf + TOT);   // Xb bf16
    ushort* U2 = U1 + TOT;              // XTT; later g (attn1 out)
    float* Af  = (float*)U1;            // fp32, live only after U1/U2 dead
    ushort* U3 = U2 + TOT;              // x1b; later gat bf16; later xn bf16
    ushort* U4 = U3 + TOT;              // WhT; later h bf16
    ushort* ADPB = U4 + TOT;            // [1024][1024]
    ushort* WMLPB = ADPB + (long)1024 * 1024;
    ushort* WG0T = WMLPB + 131072;
    ushort* WGOT = WG0T + 65536;
    ushort* WGIB = WGOT + 65536;        // [512][256] interleaved g1/g2
    ushort* WG3B = WGIB + 131072;
    float* BIASI = (float*)(WG3B + 65536);  // 512
    float* VA = BIASI + 512;                // 1024
    float* W1V = VA + 1024;
    float* W2V = W1V + 49152;
    float* W2M = W2V + 49152;               // 48 (+pad)
    uint* MASKW = (uint*)(W2M + 64);        // 32768
    float2* PART = (float2*)(MASKW + 32768); // [48][256]
    float2* STATS = PART + 48 * 256;
    float* WT = (float*)(STATS + 48);
    float* BT2 = WT + SLAB;

    dim3 blk(256);
    // prep
    k_wt2<<<dim3(4, 4, 2), blk, 0, stream>>>(Wg0, WG0T, Wgo, WGOT);
    k_wconv<<<512, blk, 0, stream>>>(Wmlp, WMLPB);
    k_wconv<<<256, blk, 0, stream>>>(Wg3, WG3B);
    k_wgi<<<512, blk, 0, stream>>>(Wg1, bg1, Wg2, bg2, WGIB, BIASI);
    k_va<<<256, blk, 0, stream>>>(Wg0, ag0, VA);
    k_va<<<256, blk, 0, stream>>>(Wgo, ago, VA + 512);
    k_wtprep<<<1024, blk, 0, stream>>>(wgt, bia, WT, BT2);
    k_adp<<<1024, blk, 0, stream>>>(nv1, nv2, ADPB);
    k_maskpack<<<128, blk, 0, stream>>>(dg, MASKW);
    k_tin<<<dim3(192, 4, 4), blk, 0, stream>>>(x_in, U1, XTf);
    k_xtt<<<dim3(16, 4, 48), blk, 0, stream>>>(U1, U2);
    // x1 = adp @ x  (Bt = XTT) -> U3 bf16
    k_bgemm<1, 0><<<dim3(8, 2, 48), blk, 0, stream>>>(ADPB, 0, nullptr, 0, 1024, 0, 1024,
                                                      U2, SLAB, nullptr, nullptr, U3, SLAB, nullptr);
    // gcn = [x|x1] @ Wmlp(o,c) + b -> Bf fp32
    k_bgemm<2, 0><<<dim3(8, 2, 48), blk, 0, stream>>>(U1, SLAB, U3, SLAB, 256, 256, 512,
                                                      WMLPB, 0, bmlp, Bf, nullptr, SLAB, nullptr);
    // GAT layer 1
    k_dots<<<12288, blk, 0, stream>>>(U1, VA, W1V, W2V);
    k_w2max<<<48, blk, 0, stream>>>(W2V, W2M);
    k_bgemm<1, 0><<<dim3(2, 8, 48), blk, 0, stream>>>(WG0T, 0, nullptr, 0, 256, 0, 256,
                                                      U1, SLAB, nullptr, nullptr, U4, SLAB, nullptr);
    k_attn_mf<<<768, blk, 0, stream>>>(U4, W1V, W2V, W2M, MASKW, U2);
    // GAT layer 2
    k_dots<<<12288, blk, 0, stream>>>(U2, VA + 512, W1V, W2V);
    k_w2max<<<48, blk, 0, stream>>>(W2V, W2M);
    k_bgemm<1, 0><<<dim3(2, 8, 48), blk, 0, stream>>>(WGOT, 0, nullptr, 0, 256, 0, 256,
                                                      U2, SLAB, nullptr, nullptr, U4, SLAB, nullptr);
    k_attn_mf<<<768, blk, 0, stream>>>(U4, W1V, W2V, W2M, MASKW, U3);
    // fuse + LN1 partials -> Af, PART
    k_fuse_ln<<<dim3(256, 48), blk, 0, stream>>>(U3, (const float4*)Bf, (const float4*)XTf,
                                                 alpha, (float4*)Af, PART);
    k_stats256<<<48, blk, 0, stream>>>(PART, STATS);
    k_ln_apply<<<12288, blk, 0, stream>>>((const float4*)Af, STATS, U3);
    // GLU pair GEMM (interleaved) -> U4 h bf16
    k_bgemm<1, 1><<<dim3(8, 4, 48), blk, 0, stream>>>(U3, SLAB, nullptr, 0, 256, 0, 256,
                                                      WGIB, 0, nullptr, nullptr, U4, SLAB, BIASI);
    // glu_out = h @ Wg3 -> XTf fp32
    k_bgemm<1, 0><<<dim3(8, 2, 48), blk, 0, stream>>>(U4, SLAB, nullptr, 0, 256, 0, 256,
                                                      WG3B, 0, bg3, XTf, nullptr, SLAB, nullptr);
    // (glu + LN1(Af))*(1+w) + bias + LN2 partials -> Bf, PART
    k_finpre_ln<<<dim3(256, 48), blk, 0, stream>>>((const float4*)XTf, (const float4*)Af,
                                                   STATS, (const float4*)WT, (const float4*)BT2,
                                                   (float4*)Bf, PART);
    k_stats256<<<48, blk, 0, stream>>>(PART, STATS);
    k_out<<<dim3(1024, 4), blk, 0, stream>>>(Bf, STATS, out);
}

// Round 8
// 479.117 us; speedup vs baseline: 4.8097x; 1.0483x over previous
//
#include <hip/hip_runtime.h>
#include <hip/hip_bf16.h>
#include <math.h>

#define DI __device__ __forceinline__
#define AS1 __attribute__((address_space(1)))
#define AS3 __attribute__((address_space(3)))

static constexpr int  B_ = 4, C_ = 256, N_ = 1024, L_ = 12, BL_ = 48;
static constexpr long SLAB = (long)N_ * C_;          // 262144 elems per (b,l)
static constexpr long TOT  = (long)BL_ * SLAB;       // 12,582,912 elems

typedef __attribute__((ext_vector_type(8))) short bf16x8;
typedef __attribute__((ext_vector_type(4))) float f32x4;

DI float b2f(uint hw) { return __builtin_bit_cast(float, (hw & 0xffffu) << 16); }
DI ushort f2b(float f) {
    uint u = __builtin_bit_cast(uint, f);
    u += 0x7FFFu + ((u >> 16) & 1u);
    return (ushort)(u >> 16);
}
DI uint pack2(float a, float b) {
    __hip_bfloat162 h = __float22bfloat162_rn(make_float2(a, b));
    uint r;
    __builtin_memcpy(&r, &h, 4);
    return r;
}

DI void gload16(const void* g, void* l) {
    __builtin_amdgcn_global_load_lds((AS1 uint*)g, (AS3 uint*)l, 16, 0, 0);
}

// ---------------- block reductions (256 threads, 4 waves) ----------------
DI float block_sum256(float v, float* sc) {
    #pragma unroll
    for (int o = 32; o > 0; o >>= 1) v += __shfl_xor(v, o, 64);
    int wid = threadIdx.x >> 6;
    __syncthreads();
    if ((threadIdx.x & 63) == 0) sc[wid] = v;
    __syncthreads();
    return sc[0] + sc[1] + sc[2] + sc[3];
}
DI float block_max256(float v, float* sc) {
    #pragma unroll
    for (int o = 32; o > 0; o >>= 1) v = fmaxf(v, __shfl_xor(v, o, 64));
    int wid = threadIdx.x >> 6;
    __syncthreads();
    if ((threadIdx.x & 63) == 0) sc[wid] = v;
    __syncthreads();
    return fmaxf(fmaxf(sc[0], sc[1]), fmaxf(sc[2], sc[3]));
}

// ---------------- adp = softmax(relu(nv1@nv2), axis=1), bf16 out ----------------
__global__ __launch_bounds__(256) void k_adp(const float* __restrict__ nv1,
                                             const float* __restrict__ nv2,
                                             ushort* __restrict__ adp) {
    __shared__ float r[6];
    __shared__ float sc[4];
    int row = blockIdx.x, tid = threadIdx.x;
    if (tid < 6) r[tid] = nv1[row * 6 + tid];
    __syncthreads();
    float e[4];
    #pragma unroll
    for (int q = 0; q < 4; q++) {
        int j = tid + q * 256;
        float s = 0.f;
        #pragma unroll
        for (int k = 0; k < 6; k++) s += r[k] * nv2[k * 1024 + j];
        e[q] = s > 0.f ? s : 0.f;
    }
    float m = fmaxf(fmaxf(e[0], e[1]), fmaxf(e[2], e[3]));
    m = block_max256(m, sc);
    float ps = 0.f;
    #pragma unroll
    for (int q = 0; q < 4; q++) { e[q] = __expf(e[q] - m); ps += e[q]; }
    ps = block_sum256(ps, sc);
    float rinv = 1.f / ps;
    #pragma unroll
    for (int q = 0; q < 4; q++) adp[(long)row * 1024 + tid + q * 256] = f2b(e[q] * rinv);
}

// ------- transpose in: x[b][c][n][l] -> Xb[(b*12+l)][n][c] bf16 + fp32 copy -------
__global__ __launch_bounds__(256) void k_tin(const float* __restrict__ x,
                                             ushort* __restrict__ xb,
                                             float* __restrict__ xf) {
    __shared__ float t[64][65];
    int nl0 = blockIdx.x * 64, c0 = blockIdx.y * 64, b = blockIdx.z;
    int lx = threadIdx.x & 63, ly = threadIdx.x >> 6;
    #pragma unroll
    for (int i = 0; i < 16; i++) {
        int c = c0 + ly + i * 4;
        t[ly + i * 4][lx] = x[(long)(b * 256 + c) * 12288 + nl0 + lx];
    }
    __syncthreads();
    #pragma unroll
    for (int i = 0; i < 16; i++) {
        int nl = nl0 + ly + i * 4;
        int n = nl / 12, l = nl % 12;
        long idx = ((long)(b * 12 + l) * 1024 + n) * 256 + c0 + lx;
        float v = t[lx][ly + i * 4];
        xb[idx] = f2b(v);
        xf[idx] = v;
    }
}

// ---------------- per-bl transpose Xb[n][c] -> XTT[c][n] (bf16) ----------------
__global__ __launch_bounds__(256) void k_xtt(const ushort* __restrict__ X,
                                             ushort* __restrict__ XT) {
    __shared__ ushort t[64][68];
    int bl = blockIdx.z;
    int n0 = blockIdx.x * 64, c0 = blockIdx.y * 64;
    int lx = threadIdx.x & 63, ly = threadIdx.x >> 6;
    const ushort* Xp = X + (long)bl * SLAB;
    #pragma unroll
    for (int i = 0; i < 16; i++)
        t[ly + i * 4][lx] = Xp[(long)(n0 + ly + i * 4) * 256 + c0 + lx];
    __syncthreads();
    ushort* Tp = XT + (long)bl * SLAB;
    #pragma unroll
    for (int i = 0; i < 16; i++)
        Tp[(long)(c0 + ly + i * 4) * 1024 + n0 + lx] = t[lx][ly + i * 4];
}

// -------- GAT weight transposes 256x256 fp32 [c][o] -> bf16 [o][c] --------
__global__ __launch_bounds__(256) void k_wt2(const float* __restrict__ S0, ushort* __restrict__ D0,
                                             const float* __restrict__ S1, ushort* __restrict__ D1) {
    __shared__ float t[64][65];
    const float* S = blockIdx.z ? S1 : S0;
    ushort* D = blockIdx.z ? D1 : D0;
    int c0 = blockIdx.x * 64, o0 = blockIdx.y * 64;
    int lx = threadIdx.x & 63, ly = threadIdx.x >> 6;
    #pragma unroll
    for (int i = 0; i < 16; i++)
        t[ly + i * 4][lx] = S[(long)(c0 + ly + i * 4) * 256 + o0 + lx];
    __syncthreads();
    #pragma unroll
    for (int i = 0; i < 16; i++)
        D[(long)(o0 + ly + i * 4) * 256 + c0 + lx] = f2b(t[lx][ly + i * 4]);
}

// ---------------- fp32 -> bf16 straight cast ----------------
__global__ __launch_bounds__(256) void k_wconv(const float* __restrict__ S, ushort* __restrict__ D) {
    long i = (long)blockIdx.x * 256 + threadIdx.x;
    D[i] = f2b(S[i]);
}

// ------- interleaved GLU weights: WGI[p*32+q] = (q<16 ? Wg1 : Wg2) row p*16+q%16 -------
__global__ __launch_bounds__(256) void k_wgi(const float* __restrict__ W1, const float* __restrict__ b1,
                                             const float* __restrict__ W2, const float* __restrict__ b2,
                                             ushort* __restrict__ WGI, float* __restrict__ BI) {
    int n = blockIdx.x, p = n >> 5, q = n & 31;
    const float* src = (q < 16) ? W1 + (long)(p * 16 + q) * 256
                                : W2 + (long)(p * 16 + q - 16) * 256;
    WGI[(long)n * 256 + threadIdx.x] = f2b(src[threadIdx.x]);
    if (threadIdx.x == 0) BI[n] = (q < 16) ? b1[p * 16 + q] : b2[p * 16 + q - 16];
}

// ----- va = W @ a pair -----
__global__ __launch_bounds__(256) void k_va(const float* __restrict__ W, const float* __restrict__ a,
                                            float* __restrict__ va) {
    __shared__ float sc[4];
    int c = blockIdx.x, t = threadIdx.x;
    float w = W[(long)c * 256 + t];
    float s1 = block_sum256(w * a[t], sc);
    float s2 = block_sum256(w * a[256 + t], sc);
    if (t == 0) { va[c] = s1; va[256 + c] = s2; }
}

// ------- weight/bias prep: wt[n][c] = w[c][n]+1, bt[n][c] = b[c][n] -------
__global__ __launch_bounds__(256) void k_wtprep(const float* __restrict__ w,
                                                const float* __restrict__ b,
                                                float* __restrict__ wt,
                                                float* __restrict__ bt) {
    int n = blockIdx.x, c = threadIdx.x;
    wt[(long)n * 256 + c] = w[(long)c * 1024 + n] + 1.f;
    bt[(long)n * 256 + c] = b[(long)c * 1024 + n];
}

// ------- pack mask bits -------
__global__ __launch_bounds__(256) void k_maskpack(const int* __restrict__ dg,
                                                  uint* __restrict__ maskw) {
    int w = blockIdx.x * 256 + threadIdx.x;
    int row = w >> 5, wo = w & 31;
    uint m = 0;
    #pragma unroll
    for (int b = 0; b < 32; b++)
        m |= (dg[(long)row * 1024 + wo * 32 + b] > 0 ? 1u : 0u) << b;
    maskw[w] = m;
}

// ------- bf16 MFMA GEMM, 2-phase pipelined: C[m][n] = sum_k A[m][k]*Bt[n][k] (+bias) ----
template<int NPAIR, int GLU>
__global__ __launch_bounds__(256) void k_bgemm(
    const ushort* __restrict__ A0, long sA0,
    const ushort* __restrict__ A1, long sA1,
    int lda, int K0, int KK,
    const ushort* __restrict__ Bt, long sBt,
    const float* __restrict__ bias,
    float* __restrict__ Cf, ushort* __restrict__ Cb, long sC,
    const float* __restrict__ biasi) {
    __shared__ ushort As[2][128 * 32];
    __shared__ ushort Bs[2][128 * 32];
    const int tid = threadIdx.x;
    const int bl = blockIdx.z;
    const int m0 = blockIdx.x * 128, n0 = blockIdx.y * 128;
    const int N = gridDim.y * 128;
    const int lane = tid & 63, w = tid >> 6;
    const int wm = (w >> 1) * 64, wn = (w & 1) * 64;
    const int sr = tid >> 2, sk = (tid & 3) * 8;
    const int fr = lane & 15, fk = (lane >> 4) * 8;
    f32x4 acc[4][4] = {};
    const ushort* Ab0 = A0 + (long)bl * sA0;
    const ushort* Ab1 = (NPAIR == 2) ? A1 + (long)bl * sA1 : nullptr;
    const ushort* Bb = Bt + (long)bl * sBt;

    auto stage = [&](int buf, int k0) {
        const ushort* Asrc = Ab0; int kl = k0;
        if (NPAIR == 2 && k0 >= K0) { Asrc = Ab1; kl = k0 - K0; }
        gload16(&Asrc[(long)(m0 + sr) * lda + kl + sk],      &As[buf][sr * 32 + sk]);
        gload16(&Asrc[(long)(m0 + sr + 64) * lda + kl + sk], &As[buf][(sr + 64) * 32 + sk]);
        gload16(&Bb[(long)(n0 + sr) * KK + k0 + sk],         &Bs[buf][sr * 32 + sk]);
        gload16(&Bb[(long)(n0 + sr + 64) * KK + k0 + sk],    &Bs[buf][(sr + 64) * 32 + sk]);
    };
    auto compute = [&](int buf) {
        bf16x8 af[4], bg[4];
        #pragma unroll
        for (int i = 0; i < 4; i++) {
            af[i] = *(const bf16x8*)&As[buf][(wm + i * 16 + fr) * 32 + fk];
            bg[i] = *(const bf16x8*)&Bs[buf][(wn + i * 16 + fr) * 32 + fk];
        }
        #pragma unroll
        for (int i = 0; i < 4; i++)
            #pragma unroll
            for (int j = 0; j < 4; j++)
                acc[i][j] = __builtin_amdgcn_mfma_f32_16x16x32_bf16(af[i], bg[j], acc[i][j], 0, 0, 0);
    };

    stage(0, 0);
    __syncthreads();                       // drains vmcnt(0)
    int cur = 0;
    for (int k0 = 32; k0 < KK; k0 += 32) {
        stage(cur ^ 1, k0);                // issue next tile, in flight under compute
        compute(cur);
        __syncthreads();                   // next tile landed + all waves done reading cur
        cur ^= 1;
    }
    compute(cur);

    const int cn = lane & 15, rb = (lane >> 4) * 4;
    if (GLU) {
        #pragma unroll
        for (int nt = 0; nt < 4; nt += 2) {
            int n1 = n0 + wn + nt * 16 + cn;          // interleaved col (g1 half)
            int hcol = ((n1 >> 5) << 4) + cn;         // original col p*16+cn
            float b1 = biasi[n1], b2 = biasi[n1 + 16];
            #pragma unroll
            for (int i = 0; i < 4; i++) {
                #pragma unroll
                for (int r = 0; r < 4; r++) {
                    int m = m0 + wm + i * 16 + rb + r;
                    float g1 = acc[i][nt][r] + b1;
                    float g2 = acc[i][nt + 1][r] + b2;
                    float h = g1 / (1.f + __expf(-g2));
                    Cb[(long)bl * sC + (long)m * 256 + hcol] = f2b(h);
                }
            }
        }
    } else {
        #pragma unroll
        for (int j = 0; j < 4; j++) {
            int n = n0 + wn + j * 16 + cn;
            float bv = bias ? bias[n] : 0.f;
            #pragma unroll
            for (int i = 0; i < 4; i++) {
                #pragma unroll
                for (int r = 0; r < 4; r++) {
                    int m = m0 + wm + i * 16 + rb + r;
                    float v = acc[i][j][r] + bv;
                    long idx = (long)bl * sC + (long)m * N + n;
                    if (Cf) Cf[idx] = v;
                    if (Cb) Cb[idx] = f2b(v);
                }
            }
        }
    }
}

// ---------------- w1/w2 GEMV ----------------
__global__ __launch_bounds__(256) void k_dots(const ushort* __restrict__ X,
                                              const float* __restrict__ va,
                                              float* __restrict__ o1,
                                              float* __restrict__ o2) {
    int wid = threadIdx.x >> 6, lane = threadIdx.x & 63;
    long row = (long)blockIdx.x * 4 + wid;
    uint2 xv = *(const uint2*)(X + row * 256 + lane * 4);
    float x0 = b2f(xv.x), x1 = b2f(xv.x >> 16), x2 = b2f(xv.y), x3 = b2f(xv.y >> 16);
    float4 v1 = *(const float4*)&va[lane * 4];
    float4 v2 = *(const float4*)&va[256 + lane * 4];
    float s1 = x0 * v1.x + x1 * v1.y + x2 * v1.z + x3 * v1.w;
    float s2 = x0 * v2.x + x1 * v2.y + x2 * v2.z + x3 * v2.w;
    #pragma unroll
    for (int o = 32; o > 0; o >>= 1) { s1 += __shfl_xor(s1, o, 64); s2 += __shfl_xor(s2, o, 64); }
    if (lane == 0) { o1[row] = s1; o2[row] = s2; }
}

// ------- per-bl global max of w2 (any m >= row max is exact after normalization) -------
__global__ __launch_bounds__(256) void k_w2max(const float* __restrict__ w2v,
                                               float* __restrict__ w2m) {
    __shared__ float sc[4];
    int bl = blockIdx.x;
    float4 v = *(const float4*)&w2v[(long)bl * 1024 + threadIdx.x * 4];
    float m = fmaxf(fmaxf(v.x, v.y), fmaxf(v.z, v.w));
    m = block_max256(m, sc);
    if (threadIdx.x == 0) w2m[bl] = m;
}

// ------- MFMA attention v5: T15 double-pipeline — computeP(jc+1) overlaps MFMA(jc) ----
__global__ __launch_bounds__(256, 3) void k_attn_mf(
    const ushort* __restrict__ WhT,   // [48][256][1024] bf16
    const float* __restrict__ w1v, const float* __restrict__ w2v,
    const float* __restrict__ w2m,    // [48]
    const uint* __restrict__ maskw,   // [1024][32]
    ushort* __restrict__ outB) {
    __shared__ ushort PA[16 * 64 * 8];   // 16 KB
    __shared__ ushort PB[16 * 64 * 8];   // 16 KB
    __shared__ float w2s[1024];
    __shared__ float w1s[64];
    __shared__ uint msk[64 * 33];        // padded stride 33
    __shared__ float psum[4][64];
    __shared__ float rsv[64];
    int d = blockIdx.x;                  // 768 blocks
    int lidx = (d & 7) * 96 + (d >> 3);  // XCD-chunked: 6 bl per XCD
    int bl = lidx >> 4;
    int i0 = (lidx & 15) * 64;
    int tid = threadIdx.x;
    #pragma unroll
    for (int q = 0; q < 4; q++) w2s[tid + q * 256] = w2v[(long)bl * 1024 + tid + q * 256];
    if (tid < 64) w1s[tid] = w1v[(long)bl * 1024 + i0 + tid];
    {   // mask load: 2048 words, coalesced, store at padded stride
        const uint4* gm = (const uint4*)(maskw + (long)i0 * 32);
        uint4 ma = gm[tid * 2], mb = gm[tid * 2 + 1];
        int r0 = tid >> 2, w0 = (tid & 3) * 8;
        uint* mp = &msk[r0 * 33 + w0];
        mp[0] = ma.x; mp[1] = ma.y; mp[2] = ma.z; mp[3] = ma.w;
        mp[4] = mb.x; mp[5] = mb.y; mp[6] = mb.z; mp[7] = mb.w;
    }
    __syncthreads();
    const int row = tid & 63, jt = tid >> 6;
    const float w1r = w1s[row];
    float e0 = w1r + w2m[bl];
    const float mr = (e0 > 0.f) ? e0 : 0.2f * e0;   // >= every masked score in row
    float sloc = 0.f;
    const int lane = tid & 63, w = tid >> 6;
    const int wn = w * 64;
    const int fr = lane & 15, fk8 = (lane >> 4) * 8;
    f32x4 acc[4][4] = {};
    const ushort* bp = WhT + (long)bl * SLAB;

    auto computeP = [&](int jc, ushort* Pb) {
        int j0 = jc * 128;
        uint mw = msk[row * 33 + jc * 4 + jt];       // thread's 32-j strip
        #pragma unroll
        for (int u = 0; u < 4; u++) {
            uint mg = mw >> (u * 8);
            int jb = j0 + jt * 32 + u * 8;
            float p[8];
            #pragma unroll
            for (int t = 0; t < 8; t++) {
                float e = w1r + w2s[jb + t];
                e = (e > 0.f) ? e : 0.2f * e;
                float pp = __expf(e - mr);
                p[t] = ((mg >> t) & 1) ? pp : 0.f;
                sloc += p[t];
            }
            uint4 pv;
            pv.x = pack2(p[0], p[1]);
            pv.y = pack2(p[2], p[3]);
            pv.z = pack2(p[4], p[5]);
            pv.w = pack2(p[6], p[7]);
            *(uint4*)((char*)Pb + ((jt * 4 + u) * 64 + row) * 16) = pv;
        }
    };
    auto mfmaC = [&](int jc, const ushort* Pb) {
        int j0 = jc * 128;
        #pragma unroll
        for (int ks = 0; ks < 4; ks++) {
            int kb = ks * 32 + fk8;
            bf16x8 bg[4], af[4];
            #pragma unroll
            for (int nt = 0; nt < 4; nt++)
                bg[nt] = *(const bf16x8*)&bp[(long)(wn + nt * 16 + fr) * 1024 + j0 + kb];
            int kq = ks * 4 + (lane >> 4);
            #pragma unroll
            for (int mt = 0; mt < 4; mt++)
                af[mt] = *(const bf16x8*)((const char*)Pb + (kq * 64 + mt * 16 + fr) * 16);
            #pragma unroll
            for (int mt = 0; mt < 4; mt++)
                #pragma unroll
                for (int nt = 0; nt < 4; nt++)
                    acc[mt][nt] = __builtin_amdgcn_mfma_f32_16x16x32_bf16(
                        af[mt], bg[nt], acc[mt][nt], 0, 0, 0);
        }
    };

    computeP(0, PA);
    __syncthreads();
    #pragma unroll 1
    for (int jc = 0; jc < 6; jc += 2) {
        computeP(jc + 1, PB);
        mfmaC(jc, PA);
        __syncthreads();
        computeP(jc + 2, PA);
        mfmaC(jc + 1, PB);
        __syncthreads();
    }
    computeP(7, PB);
    psum[jt][row] = sloc;
    mfmaC(6, PA);
    __syncthreads();
    if (tid < 64)
        rsv[tid] = 1.f / (psum[0][tid] + psum[1][tid] + psum[2][tid] + psum[3][tid]);
    mfmaC(7, PB);
    __syncthreads();
    #pragma unroll
    for (int mt = 0; mt < 4; mt++) {
        #pragma unroll
        for (int r = 0; r < 4; r++) {
            int i = mt * 16 + (lane >> 4) * 4 + r;
            float sc = rsv[i];
            #pragma unroll
            for (int nt = 0; nt < 4; nt++) {
                int c = wn + nt * 16 + fr;
                float v = acc[mt][nt][r] * sc;
                v = (v > 0.f) ? v : __expf(v) - 1.f;       // elu
                outB[(long)bl * SLAB + (long)(i0 + i) * 256 + c] = f2b(v);
            }
        }
    }
}

// ------- fuse: a_s*gat(bf16) + (1-a_s)*gcn(f32) + x_in(f32), + LN partials -------
__global__ __launch_bounds__(256) void k_fuse_ln(const ushort* __restrict__ gat,
                                                 const float4* __restrict__ gcn,
                                                 const float4* __restrict__ xf,
                                                 const float* __restrict__ alpha,
                                                 float4* __restrict__ o,
                                                 float2* __restrict__ part) {
    __shared__ float sc[4];
    int bl = blockIdx.y;
    long i = (long)bl * 65536 + blockIdx.x * 256 + threadIdx.x;
    float as = 1.f / (1.f + __expf(-alpha[0]));
    float bs = 1.f - as;
    uint2 hv = ((const uint2*)gat)[i];
    float4 g = gcn[i], x = xf[i];
    float4 v = make_float4(as * b2f(hv.x) + bs * g.x + x.x,
                           as * b2f(hv.x >> 16) + bs * g.y + x.y,
                           as * b2f(hv.y) + bs * g.z + x.z,
                           as * b2f(hv.y >> 16) + bs * g.w + x.w);
    o[i] = v;
    float s = v.x + v.y + v.z + v.w;
    float q = v.x * v.x + v.y * v.y + v.z * v.z + v.w * v.w;
    s = block_sum256(s, sc);
    q = block_sum256(q, sc);
    if (threadIdx.x == 0) part[bl * 256 + blockIdx.x] = make_float2(s, q);
}

// ------- stats from 256 partials per slab -------
__global__ __launch_bounds__(256) void k_stats256(const float2* __restrict__ part,
                                                  float2* __restrict__ stats) {
    __shared__ float sc[4];
    int bl = blockIdx.x;
    float2 v = part[bl * 256 + threadIdx.x];
    float s = block_sum256(v.x, sc);
    float q = block_sum256(v.y, sc);
    if (threadIdx.x == 0) {
        float mean = s / (float)SLAB;
        float var = q / (float)SLAB - mean * mean;
        stats[bl] = make_float2(mean, 1.f / sqrtf(var + 1e-5f));
    }
}

// ------- LN apply, bf16 out only -------
__global__ __launch_bounds__(256) void k_ln_apply(const float4* __restrict__ x,
                                                  const float2* __restrict__ stats,
                                                  ushort* __restrict__ ob) {
    long i = (long)blockIdx.x * 256 + threadIdx.x;
    int bl = (int)(i >> 16);
    float2 st = stats[bl];
    float4 v = x[i];
    uint2 ow;
    ow.x = pack2((v.x - st.x) * st.y, (v.y - st.x) * st.y);
    ow.y = pack2((v.z - st.x) * st.y, (v.w - st.x) * st.y);
    ((uint2*)ob)[i] = ow;
}

// ------- final pre-LN: (glu + LN1(afull))*(1+w) + bias, + LN2 partials -------
__global__ __launch_bounds__(256) void k_finpre_ln(const float4* __restrict__ glu,
                                                   const float4* __restrict__ afull,
                                                   const float2* __restrict__ stats1,
                                                   const float4* __restrict__ wt,
                                                   const float4* __restrict__ bt,
                                                   float4* __restrict__ o,
                                                   float2* __restrict__ part) {
    __shared__ float sc[4];
    int bl = blockIdx.y;
    long i = (long)bl * 65536 + blockIdx.x * 256 + threadIdx.x;
    long wi = i & 65535;
    float2 st = stats1[bl];
    float4 g = glu[i], a = afull[i], w = wt[wi], b = bt[wi];
    float4 v = make_float4((g.x + (a.x - st.x) * st.y) * w.x + b.x,
                           (g.y + (a.y - st.x) * st.y) * w.y + b.y,
                           (g.z + (a.z - st.x) * st.y) * w.z + b.z,
                           (g.w + (a.w - st.x) * st.y) * w.w + b.w);
    o[i] = v;
    float s = v.x + v.y + v.z + v.w;
    float q = v.x * v.x + v.y * v.y + v.z * v.z + v.w * v.w;
    s = block_sum256(s, sc);
    q = block_sum256(q, sc);
    if (threadIdx.x == 0) part[bl * 256 + blockIdx.x] = make_float2(s, q);
}

// ------- final normalize + transpose back to [b][c][n][l] -------
__global__ __launch_bounds__(256) void k_out(const float* __restrict__ x,
                                             const float2* __restrict__ stats,
                                             float* __restrict__ out) {
    int n = blockIdx.x, b = blockIdx.y, c = threadIdx.x;
    float v[12];
    #pragma unroll
    for (int l = 0; l < 12; l++) {
        float2 st = stats[b * 12 + l];
        float t = x[(long)(b * 12 + l) * SLAB + (long)n * 256 + c];
        v[l] = (t - st.x) * st.y;
    }
    float4* op = (float4*)(out + ((long)(b * 256 + c) * 1024 + n) * 12);
    op[0] = make_float4(v[0], v[1], v[2], v[3]);
    op[1] = make_float4(v[4], v[5], v[6], v[7]);
    op[2] = make_float4(v[8], v[9], v[10], v[11]);
}

// =================================================================
extern "C" void kernel_launch(void* const* d_in, const int* in_sizes, int n_in,
                              void* d_out, int out_size, void* d_ws, size_t ws_size,
                              hipStream_t stream) {
    (void)in_sizes; (void)n_in; (void)out_size; (void)ws_size;
    const float* x_in = (const float*)d_in[0];
    const int*   dg   = (const int*)d_in[1];
    const float* nv1  = (const float*)d_in[2];
    const float* nv2  = (const float*)d_in[3];
    const float* Wmlp = (const float*)d_in[4];
    const float* bmlp = (const float*)d_in[5];
    const float* Wg0  = (const float*)d_in[6];
    const float* ag0  = (const float*)d_in[7];
    const float* Wgo  = (const float*)d_in[8];
    const float* ago  = (const float*)d_in[9];
    const float* Wg1  = (const float*)d_in[10];
    const float* bg1  = (const float*)d_in[11];
    const float* Wg2  = (const float*)d_in[12];
    const float* bg2  = (const float*)d_in[13];
    const float* Wg3  = (const float*)d_in[14];
    const float* bg3  = (const float*)d_in[15];
    const float* alpha = (const float*)d_in[16];
    const float* wgt  = (const float*)d_in[17];
    const float* bia  = (const float*)d_in[18];
    float* out = (float*)d_out;

    // ---- workspace (~208 MB; Af aliases the dead U1+U2 region) ----
    float* XTf = (float*)d_ws;          // fp32 x_in copy; later glu3 out
    float* Bf  = XTf + TOT;             // fp32 gcn; later final pre-LN
    ushort* U1 = (ushort*)(Bf + TOT);   // Xb bf16
    ushort* U2 = U1 + TOT;              // XTT; later g (attn1 out)
    float* Af  = (float*)U1;            // fp32, live only after U1/U2 dead
    ushort* U3 = U2 + TOT;              // x1b; later gat bf16; later xn bf16
    ushort* U4 = U3 + TOT;              // WhT; later h bf16
    ushort* ADPB = U4 + TOT;            // [1024][1024]
    ushort* WMLPB = ADPB + (long)1024 * 1024;
    ushort* WG0T = WMLPB + 131072;
    ushort* WGOT = WG0T + 65536;
    ushort* WGIB = WGOT + 65536;        // [512][256] interleaved g1/g2
    ushort* WG3B = WGIB + 131072;
    float* BIASI = (float*)(WG3B + 65536);  // 512
    float* VA = BIASI + 512;                // 1024
    float* W1V = VA + 1024;
    float* W2V = W1V + 49152;
    float* W2M = W2V + 49152;               // 48 (+pad)
    uint* MASKW = (uint*)(W2M + 64);        // 32768
    float2* PART = (float2*)(MASKW + 32768); // [48][256]
    float2* STATS = PART + 48 * 256;
    float* WT = (float*)(STATS + 48);
    float* BT2 = WT + SLAB;

    dim3 blk(256);
    // prep
    k_wt2<<<dim3(4, 4, 2), blk, 0, stream>>>(Wg0, WG0T, Wgo, WGOT);
    k_wconv<<<512, blk, 0, stream>>>(Wmlp, WMLPB);
    k_wconv<<<256, blk, 0, stream>>>(Wg3, WG3B);
    k_wgi<<<512, blk, 0, stream>>>(Wg1, bg1, Wg2, bg2, WGIB, BIASI);
    k_va<<<256, blk, 0, stream>>>(Wg0, ag0, VA);
    k_va<<<256, blk, 0, stream>>>(Wgo, ago, VA + 512);
    k_wtprep<<<1024, blk, 0, stream>>>(wgt, bia, WT, BT2);
    k_adp<<<1024, blk, 0, stream>>>(nv1, nv2, ADPB);
    k_maskpack<<<128, blk, 0, stream>>>(dg, MASKW);
    k_tin<<<dim3(192, 4, 4), blk, 0, stream>>>(x_in, U1, XTf);
    k_xtt<<<dim3(16, 4, 48), blk, 0, stream>>>(U1, U2);
    // x1 = adp @ x  (Bt = XTT) -> U3 bf16
    k_bgemm<1, 0><<<dim3(8, 2, 48), blk, 0, stream>>>(ADPB, 0, nullptr, 0, 1024, 0, 1024,
                                                      U2, SLAB, nullptr, nullptr, U3, SLAB, nullptr);
    // gcn = [x|x1] @ Wmlp(o,c) + b -> Bf fp32
    k_bgemm<2, 0><<<dim3(8, 2, 48), blk, 0, stream>>>(U1, SLAB, U3, SLAB, 256, 256, 512,
                                                      WMLPB, 0, bmlp, Bf, nullptr, SLAB, nullptr);
    // GAT layer 1
    k_dots<<<12288, blk, 0, stream>>>(U1, VA, W1V, W2V);
    k_w2max<<<48, blk, 0, stream>>>(W2V, W2M);
    k_bgemm<1, 0><<<dim3(2, 8, 48), blk, 0, stream>>>(WG0T, 0, nullptr, 0, 256, 0, 256,
                                                      U1, SLAB, nullptr, nullptr, U4, SLAB, nullptr);
    k_attn_mf<<<768, blk, 0, stream>>>(U4, W1V, W2V, W2M, MASKW, U2);
    // GAT layer 2
    k_dots<<<12288, blk, 0, stream>>>(U2, VA + 512, W1V, W2V);
    k_w2max<<<48, blk, 0, stream>>>(W2V, W2M);
    k_bgemm<1, 0><<<dim3(2, 8, 48), blk, 0, stream>>>(WGOT, 0, nullptr, 0, 256, 0, 256,
                                                      U2, SLAB, nullptr, nullptr, U4, SLAB, nullptr);
    k_attn_mf<<<768, blk, 0, stream>>>(U4, W1V, W2V, W2M, MASKW, U3);
    // fuse + LN1 partials -> Af, PART
    k_fuse_ln<<<dim3(256, 48), blk, 0, stream>>>(U3, (const float4*)Bf, (const float4*)XTf,
                                                 alpha, (float4*)Af, PART);
    k_stats256<<<48, blk, 0, stream>>>(PART, STATS);
    k_ln_apply<<<12288, blk, 0, stream>>>((const float4*)Af, STATS, U3);
    // GLU pair GEMM (interleaved) -> U4 h bf16
    k_bgemm<1, 1><<<dim3(8, 4, 48), blk, 0, stream>>>(U3, SLAB, nullptr, 0, 256, 0, 256,
                                                      WGIB, 0, nullptr, nullptr, U4, SLAB, BIASI);
    // glu_out = h @ Wg3 -> XTf fp32
    k_bgemm<1, 0><<<dim3(8, 2, 48), blk, 0, stream>>>(U4, SLAB, nullptr, 0, 256, 0, 256,
                                                      WG3B, 0, bg3, XTf, nullptr, SLAB, nullptr);
    // (glu + LN1(Af))*(1+w) + bias + LN2 partials -> Bf, PART
    k_finpre_ln<<<dim3(256, 48), blk, 0, stream>>>((const float4*)XTf, (const float4*)Af,
                                                   STATS, (const float4*)WT, (const float4*)BT2,
                                                   (float4*)Bf, PART);
    k_stats256<<<48, blk, 0, stream>>>(PART, STATS);
    k_out<<<dim3(1024, 4), blk, 0, stream>>>(Bf, STATS, out);
}